// Round 1
// baseline (1595.912 us; speedup 1.0000x reference)
//
#include <hip/hip_runtime.h>
#include <math.h>

// Problem constants (reference: B=2, T=128, N=128, H=8, Dh=64, FEA=512)
#define FEA 512
#define NH 8
#define DH 64
#define BB 2
#define TT 128
#define NN 128
#define MTOT (BB*TT*NN)     // 32768 rows
#define SEG 16              // T / H
#define BETA 0.3f
#define LNEPS 1e-5f

// ---------------------------------------------------------------------------
// xt = x + te (vectorized float4; grid covers exactly E/4 elements)
// ---------------------------------------------------------------------------
__global__ void add_kernel(const float* __restrict__ x, const float* __restrict__ te,
                           float* __restrict__ xt) {
  size_t i = (size_t)blockIdx.x * blockDim.x + threadIdx.x;
  float4 a = ((const float4*)x)[i];
  float4 b = ((const float4*)te)[i];
  a.x += b.x; a.y += b.y; a.z += b.z; a.w += b.w;
  ((float4*)xt)[i] = a;
}

// ---------------------------------------------------------------------------
// C[M,512] = A[M,512] @ W[512,512] + bias   (optional relu)
// 128x128 block tile, BK=16, 256 threads, 8x8 microtile, LDS-staged.
// ---------------------------------------------------------------------------
template<int RELU>
__global__ __launch_bounds__(256) void gemm512(const float* __restrict__ A,
                                               const float* __restrict__ W,
                                               const float* __restrict__ bias,
                                               float* __restrict__ C) {
  __shared__ float As[16][132];   // A tile transposed [k][m], +4 pad (16B-aligned rows)
  __shared__ float Bs[16][128];   // B tile [k][n]
  const int tid = threadIdx.x;
  const int m0 = blockIdx.y * 128;
  const int n0 = blockIdx.x * 128;
  const int tx = tid & 15, ty = tid >> 4;
  const int ci = ty * 8, cj = tx * 8;
  float acc[8][8] = {};

  for (int k0 = 0; k0 < 512; k0 += 16) {
    #pragma unroll
    for (int it = 0; it < 2; ++it) {
      int idx = it * 256 + tid;               // 0..511
      int arow = idx >> 2, ac4 = idx & 3;     // 128 rows x 4 float4
      float4 av = *(const float4*)&A[(size_t)(m0 + arow) * 512 + k0 + ac4 * 4];
      As[ac4*4+0][arow] = av.x;
      As[ac4*4+1][arow] = av.y;
      As[ac4*4+2][arow] = av.z;
      As[ac4*4+3][arow] = av.w;
      int brow = idx >> 5, bc4 = idx & 31;    // 16 rows x 32 float4
      float4 bv = *(const float4*)&W[(size_t)(k0 + brow) * 512 + n0 + bc4 * 4];
      *(float4*)&Bs[brow][bc4*4] = bv;
    }
    __syncthreads();
    #pragma unroll
    for (int kk = 0; kk < 16; ++kk) {
      float a[8], b[8];
      *(float4*)&a[0] = *(const float4*)&As[kk][ci];
      *(float4*)&a[4] = *(const float4*)&As[kk][ci + 4];
      *(float4*)&b[0] = *(const float4*)&Bs[kk][cj];
      *(float4*)&b[4] = *(const float4*)&Bs[kk][cj + 4];
      #pragma unroll
      for (int i = 0; i < 8; ++i)
        #pragma unroll
        for (int j = 0; j < 8; ++j)
          acc[i][j] = fmaf(a[i], b[j], acc[i][j]);
    }
    __syncthreads();
  }

  float bsv[8];
  *(float4*)&bsv[0] = *(const float4*)&bias[n0 + cj];
  *(float4*)&bsv[4] = *(const float4*)&bias[n0 + cj + 4];
  #pragma unroll
  for (int i = 0; i < 8; ++i) {
    size_t rbase = (size_t)(m0 + ci + i) * 512 + n0 + cj;
    #pragma unroll
    for (int j4 = 0; j4 < 2; ++j4) {
      float4 o;
      o.x = acc[i][j4*4+0] + bsv[j4*4+0];
      o.y = acc[i][j4*4+1] + bsv[j4*4+1];
      o.z = acc[i][j4*4+2] + bsv[j4*4+2];
      o.w = acc[i][j4*4+3] + bsv[j4*4+3];
      if (RELU) {
        o.x = fmaxf(o.x, 0.f); o.y = fmaxf(o.y, 0.f);
        o.z = fmaxf(o.z, 0.f); o.w = fmaxf(o.w, 0.f);
      }
      *(float4*)&C[rbase + j4 * 4] = o;
    }
  }
}

// ---------------------------------------------------------------------------
// Fused causal attention with segment-focus reweighting.
// One block per (b, n, h); thread s owns query row s (flash-style, no score
// matrix). Output overwrites the q buffer in place (each thread reads only
// its own q row into registers before any writes happen).
// Scores = (q.k)/8, optionally *BETA outside the head's focus band; with
// 0.02-scale weights scores are O(1), so exp() without max-subtraction is
// numerically safe (fp32).
// ---------------------------------------------------------------------------
__global__ __launch_bounds__(128) void attn_kernel(const float* __restrict__ k,
                                                   const float* __restrict__ v,
                                                   float* __restrict__ qo) {
  __shared__ float ks[32][64];
  __shared__ float vs[32][64];
  const int bid = blockIdx.x;
  const int h = bid & 7;
  const int n = (bid >> 3) & 127;
  const int b = bid >> 10;
  const int s = threadIdx.x;
  const size_t tstride = (size_t)NN * FEA;                  // stride between t
  const size_t base = ((size_t)b * TT * NN + n) * FEA + (size_t)h * DH;

  float qreg[64], acc[64];
  {
    const float* qrow = qo + base + (size_t)s * tstride;
    #pragma unroll
    for (int d4 = 0; d4 < 16; ++d4) {
      float4 qv = *(const float4*)&qrow[d4 * 4];
      qreg[d4*4+0] = qv.x * 0.125f;   // fold 1/sqrt(64)
      qreg[d4*4+1] = qv.y * 0.125f;
      qreg[d4*4+2] = qv.z * 0.125f;
      qreg[d4*4+3] = qv.w * 0.125f;
    }
  }
  #pragma unroll
  for (int d = 0; d < 64; ++d) acc[d] = 0.f;
  float l = 0.f;
  const int fs = h * SEG;
  const int fe = (h == NH - 1) ? TT : fs + SEG;

  for (int t0 = 0; t0 < TT; t0 += 32) {
    __syncthreads();
    #pragma unroll
    for (int it = 0; it < 4; ++it) {
      int idx = it * 128 + threadIdx.x;     // 32 rows x 16 float4
      int row = idx >> 4, c4 = idx & 15;
      const size_t g = base + (size_t)(t0 + row) * tstride + c4 * 4;
      *(float4*)&ks[row][c4*4] = *(const float4*)&k[g];
      *(float4*)&vs[row][c4*4] = *(const float4*)&v[g];
    }
    __syncthreads();
    if (s >= t0) {
      const int tmax = min(32, s - t0 + 1);
      for (int t = 0; t < tmax; ++t) {
        float s0 = 0.f, s1 = 0.f, s2 = 0.f, s3 = 0.f;
        #pragma unroll
        for (int d4 = 0; d4 < 16; ++d4) {
          float4 kv = *(const float4*)&ks[t][d4 * 4];   // uniform addr: broadcast
          s0 = fmaf(qreg[d4*4+0], kv.x, s0);
          s1 = fmaf(qreg[d4*4+1], kv.y, s1);
          s2 = fmaf(qreg[d4*4+2], kv.z, s2);
          s3 = fmaf(qreg[d4*4+3], kv.w, s3);
        }
        const int tt = t0 + t;
        const float mult = (tt >= fs && tt < fe) ? 1.0f : BETA;
        const float p = __expf(((s0 + s1) + (s2 + s3)) * mult);
        l += p;
        #pragma unroll
        for (int d4 = 0; d4 < 16; ++d4) {
          float4 vv = *(const float4*)&vs[t][d4 * 4];
          acc[d4*4+0] = fmaf(p, vv.x, acc[d4*4+0]);
          acc[d4*4+1] = fmaf(p, vv.y, acc[d4*4+1]);
          acc[d4*4+2] = fmaf(p, vv.z, acc[d4*4+2]);
          acc[d4*4+3] = fmaf(p, vv.w, acc[d4*4+3]);
        }
      }
    }
  }

  const float inv = 1.0f / l;
  float* orow = qo + base + (size_t)s * tstride;
  #pragma unroll
  for (int d4 = 0; d4 < 16; ++d4) {
    float4 o;
    o.x = acc[d4*4+0] * inv; o.y = acc[d4*4+1] * inv;
    o.z = acc[d4*4+2] * inv; o.w = acc[d4*4+3] * inv;
    *(float4*)&orow[d4 * 4] = o;
  }
}

// ---------------------------------------------------------------------------
// y = LayerNorm(a + r) over last dim 512; one wave per row, 4 rows/block.
// ---------------------------------------------------------------------------
__global__ __launch_bounds__(256) void ln_add_kernel(const float* __restrict__ a,
                                                     const float* __restrict__ r,
                                                     float* __restrict__ y) {
  const int lane = threadIdx.x & 63;
  const int w = threadIdx.x >> 6;
  const size_t row = (size_t)blockIdx.x * 4 + w;
  const size_t off = row * FEA + (size_t)lane * 8;
  float u[8];
  float4 a0 = *(const float4*)&a[off];
  float4 a1 = *(const float4*)&a[off + 4];
  float4 r0 = *(const float4*)&r[off];
  float4 r1 = *(const float4*)&r[off + 4];
  u[0]=a0.x+r0.x; u[1]=a0.y+r0.y; u[2]=a0.z+r0.z; u[3]=a0.w+r0.w;
  u[4]=a1.x+r1.x; u[5]=a1.y+r1.y; u[6]=a1.z+r1.z; u[7]=a1.w+r1.w;
  float sum = 0.f, sq = 0.f;
  #pragma unroll
  for (int i = 0; i < 8; ++i) { sum += u[i]; sq = fmaf(u[i], u[i], sq); }
  #pragma unroll
  for (int m = 1; m < 64; m <<= 1) {
    sum += __shfl_xor(sum, m, 64);
    sq  += __shfl_xor(sq,  m, 64);
  }
  const float mean = sum * (1.0f / FEA);
  const float var = sq * (1.0f / FEA) - mean * mean;
  const float rstd = rsqrtf(var + LNEPS);
  float4 o0, o1;
  o0.x=(u[0]-mean)*rstd; o0.y=(u[1]-mean)*rstd; o0.z=(u[2]-mean)*rstd; o0.w=(u[3]-mean)*rstd;
  o1.x=(u[4]-mean)*rstd; o1.y=(u[5]-mean)*rstd; o1.z=(u[6]-mean)*rstd; o1.w=(u[7]-mean)*rstd;
  *(float4*)&y[off] = o0;
  *(float4*)&y[off + 4] = o1;
}

// ---------------------------------------------------------------------------
// Orchestration.
// ws layout: 3 activation buffers of 64 MiB (192 MiB total).
//   ws0: q -> attn-out (in place) -> h
//   ws1: k -> out1 -> h2
//   ws2: v -> y
// d_out doubles as xt scratch (xt is dead before the final LN writes d_out).
// ---------------------------------------------------------------------------
extern "C" void kernel_launch(void* const* d_in, const int* in_sizes, int n_in,
                              void* d_out, int out_size, void* d_ws, size_t ws_size,
                              hipStream_t stream) {
  const float* x  = (const float*)d_in[0];
  const float* te = (const float*)d_in[1];
  const float* Wq = (const float*)d_in[2];  const float* bq = (const float*)d_in[3];
  const float* Wk = (const float*)d_in[4];  const float* bk = (const float*)d_in[5];
  const float* Wv = (const float*)d_in[6];  const float* bv = (const float*)d_in[7];
  const float* Wo = (const float*)d_in[8];  const float* bo = (const float*)d_in[9];
  const float* W1 = (const float*)d_in[10]; const float* b1 = (const float*)d_in[11];
  const float* W2 = (const float*)d_in[12]; const float* b2 = (const float*)d_in[13];
  float* out = (float*)d_out;

  const size_t E = (size_t)MTOT * FEA;   // 16,777,216 elems = 64 MiB
  float* ws0 = (float*)d_ws;
  float* ws1 = ws0 + E;
  float* ws2 = ws1 + E;
  float* xt = out;                       // d_out as xt scratch

  dim3 gGemm(4, 256);                    // (N/128, M/128)

  // 1. xt = x + te
  add_kernel<<<E / 4 / 256, 256, 0, stream>>>(x, te, xt);
  // 2. q,k,v
  gemm512<0><<<gGemm, 256, 0, stream>>>(xt, Wq, bq, ws0);
  gemm512<0><<<gGemm, 256, 0, stream>>>(xt, Wk, bk, ws1);
  gemm512<0><<<gGemm, 256, 0, stream>>>(xt, Wv, bv, ws2);
  // 3. attention (in-place over q)
  attn_kernel<<<BB * NN * NH, 128, 0, stream>>>(ws1, ws2, ws0);
  // 4. out1 = attn @ Wo + bo
  gemm512<0><<<gGemm, 256, 0, stream>>>(ws0, Wo, bo, ws1);
  // 5. y = LN(out1 + xt)
  ln_add_kernel<<<MTOT / 4, 256, 0, stream>>>(ws1, xt, ws2);
  // 6. h = relu(y @ W1 + b1)
  gemm512<1><<<gGemm, 256, 0, stream>>>(ws2, W1, b1, ws0);
  // 7. h2 = h @ W2 + b2
  gemm512<0><<<gGemm, 256, 0, stream>>>(ws0, W2, b2, ws1);
  // 8. out = LN(h2 + y)
  ln_add_kernel<<<MTOT / 4, 256, 0, stream>>>(ws1, ws2, out);
}

// Round 4
// 613.010 us; speedup vs baseline: 2.6034x; 2.6034x over previous
//
#include <hip/hip_runtime.h>
#include <math.h>

typedef unsigned int uint;
typedef unsigned short ushort;

// Problem constants (reference: B=2, T=128, N=128, H=8, Dh=64, FEA=512)
#define FEA 512
#define NH 8
#define DH 64
#define BB 2
#define TT 128
#define NN 128
#define MTOT (BB*TT*NN)     // 32768 rows
#define SEG 16              // T / H
#define BETA 0.3f
#define LNEPS 1e-5f

typedef __attribute__((ext_vector_type(8))) short bf16x8;   // MFMA A/B frag (4 VGPRs)
typedef __attribute__((ext_vector_type(4))) float f32x4;    // MFMA C/D frag
typedef __attribute__((ext_vector_type(8))) short s16x8;    // 16B bf16 vector ld/st

static __device__ __forceinline__ ushort f2bf(float x) {    // RTNE fp32->bf16
  uint u = __float_as_uint(x);
  return (ushort)((u + 0x7FFFu + ((u >> 16) & 1u)) >> 16);
}
static __device__ __forceinline__ float b2f(short x) {      // exact bf16->fp32
  return __uint_as_float(((uint)(ushort)x) << 16);
}

// ---------------------------------------------------------------------------
// xt = x + te; write fp32 copy (residual) AND bf16 copy (GEMM operand).
// ---------------------------------------------------------------------------
__global__ __launch_bounds__(256) void add_fused(const float* __restrict__ x,
                                                 const float* __restrict__ te,
                                                 float* __restrict__ xt,
                                                 ushort* __restrict__ xtb) {
  size_t i = ((size_t)blockIdx.x * 256 + threadIdx.x) * 8;
  float4 a0 = *(const float4*)&x[i];
  float4 a1 = *(const float4*)&x[i + 4];
  float4 b0 = *(const float4*)&te[i];
  float4 b1 = *(const float4*)&te[i + 4];
  float u[8];
  u[0]=a0.x+b0.x; u[1]=a0.y+b0.y; u[2]=a0.z+b0.z; u[3]=a0.w+b0.w;
  u[4]=a1.x+b1.x; u[5]=a1.y+b1.y; u[6]=a1.z+b1.z; u[7]=a1.w+b1.w;
  *(float4*)&xt[i]     = make_float4(u[0],u[1],u[2],u[3]);
  *(float4*)&xt[i + 4] = make_float4(u[4],u[5],u[6],u[7]);
  s16x8 o;
  #pragma unroll
  for (int j = 0; j < 8; ++j) o[j] = (short)f2bf(u[j]);
  *(s16x8*)&xtb[i] = o;
}

// ---------------------------------------------------------------------------
// Convert + transpose all 6 weights fp32 [k][n] -> bf16 WT [n][k] in one kernel.
// ---------------------------------------------------------------------------
struct W6 { const float* s[6]; };

__global__ __launch_bounds__(256) void wconv(W6 w, ushort* __restrict__ dst) {
  __shared__ float t[32][33];
  const float* W = w.s[blockIdx.z];
  ushort* WT = dst + (size_t)blockIdx.z * FEA * FEA;
  const int k0 = blockIdx.y * 32, n0 = blockIdx.x * 32;
  const int tx = threadIdx.x & 31, ty = threadIdx.x >> 5;   // 32 x 8
  #pragma unroll
  for (int i = 0; i < 4; ++i)
    t[ty + i * 8][tx] = W[(size_t)(k0 + ty + i * 8) * FEA + n0 + tx];
  __syncthreads();
  #pragma unroll
  for (int i = 0; i < 4; ++i)
    WT[(size_t)(n0 + ty + i * 8) * FEA + k0 + tx] = f2bf(t[tx][ty + i * 8]);
}

// ---------------------------------------------------------------------------
// C[M,512](bf16) = A[M,512](bf16) @ WT^T + bias(f32), optional relu.
// 128x128 tile, BK=32, 256 threads (4 waves, 2x2), 4x4 16x16x32 frags/wave.
// Staging via global_load_lds width=16; LDS slots XOR-swizzled so fragment
// ds_read_b128 is 2-way (free). Swizzle applied on BOTH global source and
// LDS read (same involution).
// ---------------------------------------------------------------------------
template<int RELU>
__global__ __launch_bounds__(256) void gemm_bf(const ushort* __restrict__ A,
                                               const ushort* __restrict__ WT,
                                               const float* __restrict__ bias,
                                               ushort* __restrict__ C) {
  __shared__ ushort As[128 * 32];
  __shared__ ushort Bs[128 * 32];
  const int tid = threadIdx.x;
  const int m0 = blockIdx.y * 128;
  const int n0 = blockIdx.x * 128;
  const int lane = tid & 63;
  const int wid = tid >> 6;
  const int wm = wid >> 1, wn = wid & 1;          // 2x2 wave grid (64x64 each)
  const int lrow = lane & 15, lk = lane >> 4;     // frag row/col, k-group

  f32x4 acc[4][4] = {};                           // [m-sub][n-sub]

  // Staging map: LDS slot i (16B) <- global (r = i>>2, kq = (i&3) ^ ((r>>1)&3))
  int r_[2], kq_[2];
  #pragma unroll
  for (int c = 0; c < 2; ++c) {
    int i = c * 256 + tid;
    r_[c] = i >> 2;
    kq_[c] = (i & 3) ^ ((r_[c] >> 1) & 3);
  }

  for (int k0 = 0; k0 < 512; k0 += 32) {
    #pragma unroll
    for (int c = 0; c < 2; ++c) {
      const ushort* ga = A  + (size_t)(m0 + r_[c]) * 512 + k0 + kq_[c] * 8;
      const ushort* gb = WT + (size_t)(n0 + r_[c]) * 512 + k0 + kq_[c] * 8;
      __builtin_amdgcn_global_load_lds(
          (const __attribute__((address_space(1))) void*)ga,
          (__attribute__((address_space(3))) void*)&As[(c * 256 + tid) * 8], 16, 0, 0);
      __builtin_amdgcn_global_load_lds(
          (const __attribute__((address_space(1))) void*)gb,
          (__attribute__((address_space(3))) void*)&Bs[(c * 256 + tid) * 8], 16, 0, 0);
    }
    __syncthreads();   // compiler drains vmcnt before s_barrier

    bf16x8 af[4], bfr[4];
    #pragma unroll
    for (int s = 0; s < 4; ++s) {
      int ra = wm * 64 + s * 16 + lrow;
      int sa = ra * 4 + (lk ^ ((ra >> 1) & 3));
      af[s] = *(const bf16x8*)&As[sa * 8];
      int rb = wn * 64 + s * 16 + lrow;
      int sb = rb * 4 + (lk ^ ((rb >> 1) & 3));
      bfr[s] = *(const bf16x8*)&Bs[sb * 8];
    }
    #pragma unroll
    for (int i = 0; i < 4; ++i)
      #pragma unroll
      for (int j = 0; j < 4; ++j)
        acc[i][j] = __builtin_amdgcn_mfma_f32_16x16x32_bf16(af[i], bfr[j], acc[i][j], 0, 0, 0);
    __syncthreads();
  }

  // Epilogue: C/D layout col = lane&15, row = (lane>>4)*4 + reg.
  float bv[4];
  #pragma unroll
  for (int s = 0; s < 4; ++s) bv[s] = bias[n0 + wn * 64 + s * 16 + lrow];
  #pragma unroll
  for (int i = 0; i < 4; ++i) {
    const int grow = m0 + wm * 64 + i * 16 + lk * 4;
    #pragma unroll
    for (int j = 0; j < 4; ++j) {
      const int gcol = n0 + wn * 64 + j * 16 + lrow;
      #pragma unroll
      for (int q = 0; q < 4; ++q) {
        float o = acc[i][j][q] + bv[j];
        if (RELU) o = fmaxf(o, 0.f);
        C[(size_t)(grow + q) * 512 + gcol] = f2bf(o);
      }
    }
  }
}

// ---------------------------------------------------------------------------
// Fused causal attention + segment-focus reweighting. bf16 in/out, fp32 math.
// One block per (b,n,h); thread s owns query row s. Output in-place over q.
// Uniform masked inner loop (no divergent trip counts within a wave).
// ---------------------------------------------------------------------------
__global__ __launch_bounds__(128) void attn_bf(const ushort* __restrict__ k,
                                               const ushort* __restrict__ v,
                                               ushort* __restrict__ qo) {
  __shared__ float ks[32][64];
  __shared__ float vs[32][64];
  const int bid = blockIdx.x;
  const int h = bid & 7;
  const int n = (bid >> 3) & 127;
  const int b = bid >> 10;
  const int s = threadIdx.x;
  const size_t tstride = (size_t)NN * FEA;
  const size_t base = ((size_t)b * TT * NN + n) * FEA + (size_t)h * DH;

  float qreg[64], acc[64];
  {
    const ushort* qrow = qo + base + (size_t)s * tstride;
    #pragma unroll
    for (int c = 0; c < 8; ++c) {
      s16x8 qv = *(const s16x8*)&qrow[c * 8];
      #pragma unroll
      for (int j = 0; j < 8; ++j) qreg[c * 8 + j] = b2f(qv[j]) * 0.125f;
    }
  }
  #pragma unroll
  for (int d = 0; d < 64; ++d) acc[d] = 0.f;
  float l = 0.f;
  const int fs = h * SEG;
  const int fe = (h == NH - 1) ? TT : fs + SEG;
  const int smax = s | 63;                       // wave-uniform

  for (int t0 = 0; t0 < TT; t0 += 32) {
    __syncthreads();
    #pragma unroll
    for (int it = 0; it < 2; ++it) {
      int c = it * 128 + threadIdx.x;            // 256 chunks of 8 bf16
      int row = c >> 3, o8 = (c & 7) * 8;
      size_t g = base + (size_t)(t0 + row) * tstride + o8;
      s16x8 kk = *(const s16x8*)&k[g];
      s16x8 vv = *(const s16x8*)&v[g];
      #pragma unroll
      for (int j = 0; j < 8; ++j) {
        ks[row][o8 + j] = b2f(kk[j]);
        vs[row][o8 + j] = b2f(vv[j]);
      }
    }
    __syncthreads();
    if (t0 <= smax) {
      const int tmaxw = min(32, smax - t0 + 1);  // wave-uniform trip count
      for (int t = 0; t < tmaxw; ++t) {
        float s0 = 0.f, s1 = 0.f, s2 = 0.f, s3 = 0.f;
        #pragma unroll
        for (int d4 = 0; d4 < 16; ++d4) {
          float4 kv = *(const float4*)&ks[t][d4 * 4];   // uniform addr: broadcast
          s0 = fmaf(qreg[d4*4+0], kv.x, s0);
          s1 = fmaf(qreg[d4*4+1], kv.y, s1);
          s2 = fmaf(qreg[d4*4+2], kv.z, s2);
          s3 = fmaf(qreg[d4*4+3], kv.w, s3);
        }
        const int tt = t0 + t;
        const float mult = (tt >= fs && tt < fe) ? 1.0f : BETA;
        const float p = (tt <= s) ? __expf(((s0 + s1) + (s2 + s3)) * mult) : 0.f;
        l += p;
        #pragma unroll
        for (int d4 = 0; d4 < 16; ++d4) {
          float4 vv = *(const float4*)&vs[t][d4 * 4];
          acc[d4*4+0] = fmaf(p, vv.x, acc[d4*4+0]);
          acc[d4*4+1] = fmaf(p, vv.y, acc[d4*4+1]);
          acc[d4*4+2] = fmaf(p, vv.z, acc[d4*4+2]);
          acc[d4*4+3] = fmaf(p, vv.w, acc[d4*4+3]);
        }
      }
    }
  }

  const float inv = 1.0f / l;
  ushort* orow = qo + base + (size_t)s * tstride;
  #pragma unroll
  for (int c = 0; c < 8; ++c) {
    s16x8 o;
    #pragma unroll
    for (int j = 0; j < 8; ++j) o[j] = (short)f2bf(acc[c * 8 + j] * inv);
    *(s16x8*)&orow[c * 8] = o;
  }
}

// ---------------------------------------------------------------------------
// y = LayerNorm(a + r) over last dim 512; one wave/row, 4 rows/block.
// ABF/RBF/OBF select bf16 vs fp32 for each tensor.
// ---------------------------------------------------------------------------
template<int ABF, int RBF, int OBF>
__global__ __launch_bounds__(256) void ln_add(const void* __restrict__ a_,
                                              const void* __restrict__ r_,
                                              void* __restrict__ y_) {
  const int lane = threadIdx.x & 63;
  const int w = threadIdx.x >> 6;
  const size_t row = (size_t)blockIdx.x * 4 + w;
  const size_t off = row * FEA + (size_t)lane * 8;
  float ua[8], ur[8], u[8];
  if (ABF) {
    s16x8 v = *(const s16x8*)&((const ushort*)a_)[off];
    #pragma unroll
    for (int j = 0; j < 8; ++j) ua[j] = b2f(v[j]);
  } else {
    float4 v0 = *(const float4*)&((const float*)a_)[off];
    float4 v1 = *(const float4*)&((const float*)a_)[off + 4];
    ua[0]=v0.x; ua[1]=v0.y; ua[2]=v0.z; ua[3]=v0.w;
    ua[4]=v1.x; ua[5]=v1.y; ua[6]=v1.z; ua[7]=v1.w;
  }
  if (RBF) {
    s16x8 v = *(const s16x8*)&((const ushort*)r_)[off];
    #pragma unroll
    for (int j = 0; j < 8; ++j) ur[j] = b2f(v[j]);
  } else {
    float4 v0 = *(const float4*)&((const float*)r_)[off];
    float4 v1 = *(const float4*)&((const float*)r_)[off + 4];
    ur[0]=v0.x; ur[1]=v0.y; ur[2]=v0.z; ur[3]=v0.w;
    ur[4]=v1.x; ur[5]=v1.y; ur[6]=v1.z; ur[7]=v1.w;
  }
  float sum = 0.f, sq = 0.f;
  #pragma unroll
  for (int j = 0; j < 8; ++j) {
    u[j] = ua[j] + ur[j];
    sum += u[j];
    sq = fmaf(u[j], u[j], sq);
  }
  #pragma unroll
  for (int m = 1; m < 64; m <<= 1) {
    sum += __shfl_xor(sum, m, 64);
    sq  += __shfl_xor(sq,  m, 64);
  }
  const float mean = sum * (1.0f / FEA);
  const float var = sq * (1.0f / FEA) - mean * mean;
  const float rstd = rsqrtf(var + LNEPS);
  if (OBF) {
    s16x8 o;
    #pragma unroll
    for (int j = 0; j < 8; ++j) o[j] = (short)f2bf((u[j] - mean) * rstd);
    *(s16x8*)&((ushort*)y_)[off] = o;
  } else {
    float4 o0, o1;
    o0.x=(u[0]-mean)*rstd; o0.y=(u[1]-mean)*rstd; o0.z=(u[2]-mean)*rstd; o0.w=(u[3]-mean)*rstd;
    o1.x=(u[4]-mean)*rstd; o1.y=(u[5]-mean)*rstd; o1.z=(u[6]-mean)*rstd; o1.w=(u[7]-mean)*rstd;
    *(float4*)&((float*)y_)[off] = o0;
    *(float4*)&((float*)y_)[off + 4] = o1;
  }
}

// ---------------------------------------------------------------------------
// Orchestration.  ws (131 MiB): B0..B3 bf16 activation buffers (32 MiB each),
// WB = 6 transposed bf16 weights (3 MiB).  d_out doubles as fp32 xt scratch.
//   B0: xt_bf        -> y_bf (step 6)
//   B1: q  -> attnout (in place) -> h2_bf (step 8)
//   B2: k  -> out1_bf (step 5)
//   B3: v  -> h_bf   (step 7)
// ---------------------------------------------------------------------------
extern "C" void kernel_launch(void* const* d_in, const int* in_sizes, int n_in,
                              void* d_out, int out_size, void* d_ws, size_t ws_size,
                              hipStream_t stream) {
  const float* x  = (const float*)d_in[0];
  const float* te = (const float*)d_in[1];
  const float* bq = (const float*)d_in[3];
  const float* bk = (const float*)d_in[5];
  const float* bv = (const float*)d_in[7];
  const float* bo = (const float*)d_in[9];
  const float* b1 = (const float*)d_in[11];
  const float* b2 = (const float*)d_in[13];
  float* out = (float*)d_out;

  const size_t E = (size_t)MTOT * FEA;           // 16,777,216
  ushort* B0 = (ushort*)d_ws;
  ushort* B1 = B0 + E;
  ushort* B2 = B1 + E;
  ushort* B3 = B2 + E;
  ushort* WB = B3 + E;                           // 6 x 512 x 512
  const size_t WE = (size_t)FEA * FEA;
  float* xt = out;                               // d_out as fp32 xt scratch

  dim3 gGemm(4, 256);                            // (N/128, M/128)

  // 1. xt = x + te (fp32 + bf16)
  add_fused<<<E / 8 / 256, 256, 0, stream>>>(x, te, xt, B0);
  // 2. weights -> bf16, transposed
  W6 w;
  w.s[0] = (const float*)d_in[2];  w.s[1] = (const float*)d_in[4];
  w.s[2] = (const float*)d_in[6];  w.s[3] = (const float*)d_in[8];
  w.s[4] = (const float*)d_in[10]; w.s[5] = (const float*)d_in[12];
  wconv<<<dim3(16, 16, 6), 256, 0, stream>>>(w, WB);
  // 3. q, k, v
  gemm_bf<0><<<gGemm, 256, 0, stream>>>(B0, WB + 0 * WE, bq, B1);
  gemm_bf<0><<<gGemm, 256, 0, stream>>>(B0, WB + 1 * WE, bk, B2);
  gemm_bf<0><<<gGemm, 256, 0, stream>>>(B0, WB + 2 * WE, bv, B3);
  // 4. attention (in-place over q)
  attn_bf<<<BB * NN * NH, 128, 0, stream>>>(B2, B3, B1);
  // 5. out1 = attn @ Wo + bo
  gemm_bf<0><<<gGemm, 256, 0, stream>>>(B1, WB + 3 * WE, bo, B2);
  // 6. y = LN(out1 + xt)  -> bf16
  ln_add<1, 0, 1><<<MTOT / 4, 256, 0, stream>>>(B2, xt, B0);
  // 7. h = relu(y @ W1 + b1)
  gemm_bf<1><<<gGemm, 256, 0, stream>>>(B0, WB + 4 * WE, b1, B3);
  // 8. h2 = h @ W2 + b2
  gemm_bf<0><<<gGemm, 256, 0, stream>>>(B3, WB + 5 * WE, b2, B1);
  // 9. out = LN(h2 + y) -> fp32
  ln_add<1, 1, 0><<<MTOT / 4, 256, 0, stream>>>(B1, B0, out);
}

// Round 5
// 461.039 us; speedup vs baseline: 3.4616x; 1.3296x over previous
//
#include <hip/hip_runtime.h>
#include <math.h>

typedef unsigned int uint;
typedef unsigned short ushort;

// Problem constants (reference: B=2, T=128, N=128, H=8, Dh=64, FEA=512)
#define FEA 512
#define NH 8
#define DH 64
#define BB 2
#define TT 128
#define NN 128
#define MTOT (BB*TT*NN)     // 32768 rows
#define SEG 16              // T / H
#define BETA 0.3f
#define LNEPS 1e-5f

typedef __attribute__((ext_vector_type(8))) short bf16x8;   // MFMA A/B frag (4 VGPRs)
typedef __attribute__((ext_vector_type(4))) float f32x4;    // MFMA C/D frag
typedef __attribute__((ext_vector_type(8))) short s16x8;    // 16B bf16 vector ld/st

static __device__ __forceinline__ ushort f2bf(float x) {    // RTNE fp32->bf16
  uint u = __float_as_uint(x);
  return (ushort)((u + 0x7FFFu + ((u >> 16) & 1u)) >> 16);
}
static __device__ __forceinline__ float b2f(short x) {      // exact bf16->fp32
  return __uint_as_float(((uint)(ushort)x) << 16);
}

// ---------------------------------------------------------------------------
// xt = x + te; write fp32 copy (residual) AND bf16 copy (GEMM operand).
// ---------------------------------------------------------------------------
__global__ __launch_bounds__(256) void add_fused(const float* __restrict__ x,
                                                 const float* __restrict__ te,
                                                 float* __restrict__ xt,
                                                 ushort* __restrict__ xtb) {
  size_t i = ((size_t)blockIdx.x * 256 + threadIdx.x) * 8;
  float4 a0 = *(const float4*)&x[i];
  float4 a1 = *(const float4*)&x[i + 4];
  float4 b0 = *(const float4*)&te[i];
  float4 b1 = *(const float4*)&te[i + 4];
  float u[8];
  u[0]=a0.x+b0.x; u[1]=a0.y+b0.y; u[2]=a0.z+b0.z; u[3]=a0.w+b0.w;
  u[4]=a1.x+b1.x; u[5]=a1.y+b1.y; u[6]=a1.z+b1.z; u[7]=a1.w+b1.w;
  *(float4*)&xt[i]     = make_float4(u[0],u[1],u[2],u[3]);
  *(float4*)&xt[i + 4] = make_float4(u[4],u[5],u[6],u[7]);
  s16x8 o;
  #pragma unroll
  for (int j = 0; j < 8; ++j) o[j] = (short)f2bf(u[j]);
  *(s16x8*)&xtb[i] = o;
}

// ---------------------------------------------------------------------------
// Convert + transpose all 6 weights fp32 [k][n] -> bf16 WT [n][k] in one kernel.
// ---------------------------------------------------------------------------
struct W6 { const float* s[6]; };

__global__ __launch_bounds__(256) void wconv(W6 w, ushort* __restrict__ dst) {
  __shared__ float t[32][33];
  const float* W = w.s[blockIdx.z];
  ushort* WT = dst + (size_t)blockIdx.z * FEA * FEA;
  const int k0 = blockIdx.y * 32, n0 = blockIdx.x * 32;
  const int tx = threadIdx.x & 31, ty = threadIdx.x >> 5;   // 32 x 8
  #pragma unroll
  for (int i = 0; i < 4; ++i)
    t[ty + i * 8][tx] = W[(size_t)(k0 + ty + i * 8) * FEA + n0 + tx];
  __syncthreads();
  #pragma unroll
  for (int i = 0; i < 4; ++i)
    WT[(size_t)(n0 + ty + i * 8) * FEA + k0 + tx] = f2bf(t[tx][ty + i * 8]);
}

// ---------------------------------------------------------------------------
// C[M,512](bf16) = A[M,512](bf16) @ WT^T + bias(f32), optional relu.
// 128x128 tile, BK=32, 256 threads (4 waves, 2x2), 4x4 16x16x32 frags/wave.
// (unchanged from round 4 — measured working)
// ---------------------------------------------------------------------------
template<int RELU>
__global__ __launch_bounds__(256) void gemm_bf(const ushort* __restrict__ A,
                                               const ushort* __restrict__ WT,
                                               const float* __restrict__ bias,
                                               ushort* __restrict__ C) {
  __shared__ ushort As[128 * 32];
  __shared__ ushort Bs[128 * 32];
  const int tid = threadIdx.x;
  const int m0 = blockIdx.y * 128;
  const int n0 = blockIdx.x * 128;
  const int lane = tid & 63;
  const int wid = tid >> 6;
  const int wm = wid >> 1, wn = wid & 1;          // 2x2 wave grid (64x64 each)
  const int lrow = lane & 15, lk = lane >> 4;     // frag row/col, k-group

  f32x4 acc[4][4] = {};                           // [m-sub][n-sub]

  int r_[2], kq_[2];
  #pragma unroll
  for (int c = 0; c < 2; ++c) {
    int i = c * 256 + tid;
    r_[c] = i >> 2;
    kq_[c] = (i & 3) ^ ((r_[c] >> 1) & 3);
  }

  for (int k0 = 0; k0 < 512; k0 += 32) {
    #pragma unroll
    for (int c = 0; c < 2; ++c) {
      const ushort* ga = A  + (size_t)(m0 + r_[c]) * 512 + k0 + kq_[c] * 8;
      const ushort* gb = WT + (size_t)(n0 + r_[c]) * 512 + k0 + kq_[c] * 8;
      __builtin_amdgcn_global_load_lds(
          (const __attribute__((address_space(1))) void*)ga,
          (__attribute__((address_space(3))) void*)&As[(c * 256 + tid) * 8], 16, 0, 0);
      __builtin_amdgcn_global_load_lds(
          (const __attribute__((address_space(1))) void*)gb,
          (__attribute__((address_space(3))) void*)&Bs[(c * 256 + tid) * 8], 16, 0, 0);
    }
    __syncthreads();

    bf16x8 af[4], bfr[4];
    #pragma unroll
    for (int s = 0; s < 4; ++s) {
      int ra = wm * 64 + s * 16 + lrow;
      int sa = ra * 4 + (lk ^ ((ra >> 1) & 3));
      af[s] = *(const bf16x8*)&As[sa * 8];
      int rb = wn * 64 + s * 16 + lrow;
      int sb = rb * 4 + (lk ^ ((rb >> 1) & 3));
      bfr[s] = *(const bf16x8*)&Bs[sb * 8];
    }
    #pragma unroll
    for (int i = 0; i < 4; ++i)
      #pragma unroll
      for (int j = 0; j < 4; ++j)
        acc[i][j] = __builtin_amdgcn_mfma_f32_16x16x32_bf16(af[i], bfr[j], acc[i][j], 0, 0, 0);
    __syncthreads();
  }

  float bv[4];
  #pragma unroll
  for (int s = 0; s < 4; ++s) bv[s] = bias[n0 + wn * 64 + s * 16 + lrow];
  #pragma unroll
  for (int i = 0; i < 4; ++i) {
    const int grow = m0 + wm * 64 + i * 16 + lk * 4;
    #pragma unroll
    for (int j = 0; j < 4; ++j) {
      const int gcol = n0 + wn * 64 + j * 16 + lrow;
      #pragma unroll
      for (int q = 0; q < 4; ++q) {
        float o = acc[i][j][q] + bv[j];
        if (RELU) o = fmaxf(o, 0.f);
        C[(size_t)(grow + q) * 512 + gcol] = f2bf(o);
      }
    }
  }
}

// ---------------------------------------------------------------------------
// MFMA attention. One block per (b,n,h), 256 threads = 4 waves; wave w owns
// q-rows [w*32, w*32+32). Causal: wave w runs chunks 0..w of 32 t each.
// Swapped QK^T (mfma(K,Q) -> S^T: col=q, row=t) so softmax denom is a
// lane-local sum + 2 shfl_xor. P -> bf16 -> per-wave swizzled LDS buffer ->
// PV A-frags. K staged via global_load_lds (pre-swizzled source, rule #21);
// V staged transposed with bank-spread slot map (<=2-way on write and read).
// No barriers in the main loop (P-buf per-wave). Output in-place over q
// (each wave reads only its own q-rows before writing them).
// ---------------------------------------------------------------------------
__global__ __launch_bounds__(256) void attn_mfma(const ushort* __restrict__ kp,
                                                 const ushort* __restrict__ vp,
                                                 ushort* __restrict__ qo) {
  __shared__ ushort Ks[8192];      // 128t x 64d bf16, 16B slots: slot(t,gs)=t*8+(gs^(t&7))
  __shared__ ushort Vt[8192];      // V^T 64d x 128t: slot(d,ts)=d*16+(ts^(d&7)^(d>>3))
  __shared__ ushort Pb[4][1024];   // per-wave P [32q][32t]: slot(qr,ts)=qr*4+(ts^(qr&3))
  __shared__ float  Lb[4][32];     // per-wave 1/l

  const int bid = blockIdx.x;
  const int h = bid & 7;
  const int n = (bid >> 3) & 127;
  const int b = bid >> 10;
  const int tid = threadIdx.x;
  const int lane = tid & 63;
  const int w = tid >> 6;
  const int g = lane >> 4, c = lane & 15;
  const size_t tstride = (size_t)NN * FEA;
  const size_t base = ((size_t)b * TT * NN + n) * FEA + (size_t)h * DH;

  // ---- stage K via global_load_lds: LDS slot i <- K[t=i>>3][d-grp (i&7)^(t&7)]
  #pragma unroll
  for (int it = 0; it < 4; ++it) {
    int i = it * 256 + tid;
    int t = i >> 3;
    int gd = (i & 7) ^ (t & 7);
    const ushort* gk = kp + base + (size_t)t * tstride + gd * 8;
    __builtin_amdgcn_global_load_lds(
        (const __attribute__((address_space(1))) void*)gk,
        (__attribute__((address_space(3))) void*)&Ks[i * 8], 16, 0, 0);
  }
  // ---- stage V^T: coalesced 16B row-chunk loads, swizzled b16 writes
  #pragma unroll
  for (int it = 0; it < 4; ++it) {
    int j = it * 256 + tid;
    int t = j >> 3, d0 = (j & 7) * 8;
    s16x8 vv = *(const s16x8*)&vp[base + (size_t)t * tstride + d0];
    #pragma unroll
    for (int jj = 0; jj < 8; ++jj) {
      int d = d0 + jj;
      int slot = d * 16 + ((t >> 3) ^ (d & 7) ^ (d >> 3));
      Vt[slot * 8 + (t & 7)] = (ushort)vv[jj];
    }
  }
  // ---- Q fragments from global (own q-rows; 16B per lane per frag)
  const int qb = w * 32;
  bf16x8 Qf[2][2];
  #pragma unroll
  for (int qt = 0; qt < 2; ++qt)
    #pragma unroll
    for (int kf = 0; kf < 2; ++kf)
      Qf[qt][kf] = *(const bf16x8*)
          &qo[base + (size_t)(qb + qt * 16 + c) * tstride + kf * 32 + g * 8];
  __syncthreads();   // drains vmcnt (global_load_lds) + lgkm

  const int fs = h * SEG;
  const int fe = (h == NH - 1) ? TT : fs + SEG;

  f32x4 Oa[2][4];
  #pragma unroll
  for (int qt = 0; qt < 2; ++qt)
    #pragma unroll
    for (int dt = 0; dt < 4; ++dt)
      Oa[qt][dt] = (f32x4){0.f, 0.f, 0.f, 0.f};
  float lsum[2] = {0.f, 0.f};

  for (int ch = 0; ch <= w; ++ch) {
    const int tc = ch * 32;
    // ---- QK^T (swapped): S^T[t][q] for 2 t-tiles x 2 q-tiles
    f32x4 sf[2][2];
    #pragma unroll
    for (int tt2 = 0; tt2 < 2; ++tt2) {
      bf16x8 Kf[2];
      #pragma unroll
      for (int kf = 0; kf < 2; ++kf) {
        int t = tc + tt2 * 16 + c;                    // A-frag row = c
        int slot = t * 8 + ((kf * 4 + g) ^ (c & 7));  // t&7 == c&7 (t0 mult 16)
        Kf[kf] = *(const bf16x8*)&Ks[slot * 8];
      }
      #pragma unroll
      for (int qt = 0; qt < 2; ++qt) {
        f32x4 s = (f32x4){0.f, 0.f, 0.f, 0.f};
        s = __builtin_amdgcn_mfma_f32_16x16x32_bf16(Kf[0], Qf[qt][0], s, 0, 0, 0);
        s = __builtin_amdgcn_mfma_f32_16x16x32_bf16(Kf[1], Qf[qt][1], s, 0, 0, 0);
        sf[tt2][qt] = s;
      }
    }
    // ---- softmax numerator (no max-sub; scores O(1)), pack, write P-buf
    #pragma unroll
    for (int tt2 = 0; tt2 < 2; ++tt2) {
      #pragma unroll
      for (int qt = 0; qt < 2; ++qt) {
        const int q = qb + qt * 16 + c;               // D col = q
        const int qr = qt * 16 + c;                   // P-buf row
        #pragma unroll
        for (int pr = 0; pr < 2; ++pr) {
          float pv[2];
          #pragma unroll
          for (int rr = 0; rr < 2; ++rr) {
            int reg = pr * 2 + rr;
            int t = tc + tt2 * 16 + g * 4 + reg;      // D row = t
            float mult = (t >= fs && t < fe) ? 0.125f : 0.125f * BETA;
            float p = __expf(sf[tt2][qt][reg] * mult);
            p = (t <= q) ? p : 0.f;
            pv[rr] = p;
            lsum[qt] += p;
          }
          uint pk = (uint)f2bf(pv[0]) | ((uint)f2bf(pv[1]) << 16);
          int tl = tt2 * 16 + g * 4 + pr * 2;
          int slot = qr * 4 + ((tl >> 3) ^ (qr & 3));
          *(uint*)&Pb[w][slot * 8 + (tl & 7)] = pk;
        }
      }
    }
    // ---- PV: O[q][d] += P[q][t] * V[t][d] over this 32-t chunk
    bf16x8 Vf[4];
    #pragma unroll
    for (int dt = 0; dt < 4; ++dt) {
      int d = dt * 16 + c;                            // B-frag col = d
      int slot = d * 16 + ((((tc >> 3)) + g) ^ (d & 7) ^ (d >> 3));
      Vf[dt] = *(const bf16x8*)&Vt[slot * 8];
    }
    #pragma unroll
    for (int qt = 0; qt < 2; ++qt) {
      int qr = qt * 16 + c;                           // A-frag row = q
      int slot = qr * 4 + (g ^ (qr & 3));
      bf16x8 Pa = *(const bf16x8*)&Pb[w][slot * 8];
      #pragma unroll
      for (int dt = 0; dt < 4; ++dt)
        Oa[qt][dt] = __builtin_amdgcn_mfma_f32_16x16x32_bf16(Pa, Vf[dt], Oa[qt][dt], 0, 0, 0);
    }
  }

  // ---- denominators: sum the 4 g-copies per q, broadcast 1/l via LDS
  #pragma unroll
  for (int qt = 0; qt < 2; ++qt) {
    lsum[qt] += __shfl_xor(lsum[qt], 16, 64);
    lsum[qt] += __shfl_xor(lsum[qt], 32, 64);
  }
  if (g == 0) {
    Lb[w][c]      = 1.0f / lsum[0];
    Lb[w][16 + c] = 1.0f / lsum[1];
  }
  // same-wave LDS dep; compiler inserts lgkm wait, no barrier needed
  #pragma unroll
  for (int qt = 0; qt < 2; ++qt) {
    f32x4 linv = *(const f32x4*)&Lb[w][qt * 16 + g * 4];
    #pragma unroll
    for (int dt = 0; dt < 4; ++dt) {
      #pragma unroll
      for (int reg = 0; reg < 4; ++reg) {
        int q = qb + qt * 16 + g * 4 + reg;           // D row = q
        qo[base + (size_t)q * tstride + dt * 16 + c] = f2bf(Oa[qt][dt][reg] * linv[reg]);
      }
    }
  }
}

// ---------------------------------------------------------------------------
// y = LayerNorm(a + r) over last dim 512; one wave/row, 4 rows/block.
// ---------------------------------------------------------------------------
template<int ABF, int RBF, int OBF>
__global__ __launch_bounds__(256) void ln_add(const void* __restrict__ a_,
                                              const void* __restrict__ r_,
                                              void* __restrict__ y_) {
  const int lane = threadIdx.x & 63;
  const int w = threadIdx.x >> 6;
  const size_t row = (size_t)blockIdx.x * 4 + w;
  const size_t off = row * FEA + (size_t)lane * 8;
  float ua[8], ur[8], u[8];
  if (ABF) {
    s16x8 v = *(const s16x8*)&((const ushort*)a_)[off];
    #pragma unroll
    for (int j = 0; j < 8; ++j) ua[j] = b2f(v[j]);
  } else {
    float4 v0 = *(const float4*)&((const float*)a_)[off];
    float4 v1 = *(const float4*)&((const float*)a_)[off + 4];
    ua[0]=v0.x; ua[1]=v0.y; ua[2]=v0.z; ua[3]=v0.w;
    ua[4]=v1.x; ua[5]=v1.y; ua[6]=v1.z; ua[7]=v1.w;
  }
  if (RBF) {
    s16x8 v = *(const s16x8*)&((const ushort*)r_)[off];
    #pragma unroll
    for (int j = 0; j < 8; ++j) ur[j] = b2f(v[j]);
  } else {
    float4 v0 = *(const float4*)&((const float*)r_)[off];
    float4 v1 = *(const float4*)&((const float*)r_)[off + 4];
    ur[0]=v0.x; ur[1]=v0.y; ur[2]=v0.z; ur[3]=v0.w;
    ur[4]=v1.x; ur[5]=v1.y; ur[6]=v1.z; ur[7]=v1.w;
  }
  float sum = 0.f, sq = 0.f;
  #pragma unroll
  for (int j = 0; j < 8; ++j) {
    u[j] = ua[j] + ur[j];
    sum += u[j];
    sq = fmaf(u[j], u[j], sq);
  }
  #pragma unroll
  for (int m = 1; m < 64; m <<= 1) {
    sum += __shfl_xor(sum, m, 64);
    sq  += __shfl_xor(sq,  m, 64);
  }
  const float mean = sum * (1.0f / FEA);
  const float var = sq * (1.0f / FEA) - mean * mean;
  const float rstd = rsqrtf(var + LNEPS);
  if (OBF) {
    s16x8 o;
    #pragma unroll
    for (int j = 0; j < 8; ++j) o[j] = (short)f2bf((u[j] - mean) * rstd);
    *(s16x8*)&((ushort*)y_)[off] = o;
  } else {
    float4 o0, o1;
    o0.x=(u[0]-mean)*rstd; o0.y=(u[1]-mean)*rstd; o0.z=(u[2]-mean)*rstd; o0.w=(u[3]-mean)*rstd;
    o1.x=(u[4]-mean)*rstd; o1.y=(u[5]-mean)*rstd; o1.z=(u[6]-mean)*rstd; o1.w=(u[7]-mean)*rstd;
    *(float4*)&((float*)y_)[off] = o0;
    *(float4*)&((float*)y_)[off + 4] = o1;
  }
}

// ---------------------------------------------------------------------------
// Orchestration (unchanged buffers).  ws: B0..B3 bf16 (32 MiB each) + WB.
// ---------------------------------------------------------------------------
extern "C" void kernel_launch(void* const* d_in, const int* in_sizes, int n_in,
                              void* d_out, int out_size, void* d_ws, size_t ws_size,
                              hipStream_t stream) {
  const float* x  = (const float*)d_in[0];
  const float* te = (const float*)d_in[1];
  const float* bq = (const float*)d_in[3];
  const float* bk = (const float*)d_in[5];
  const float* bv = (const float*)d_in[7];
  const float* bo = (const float*)d_in[9];
  const float* b1 = (const float*)d_in[11];
  const float* b2 = (const float*)d_in[13];
  float* out = (float*)d_out;

  const size_t E = (size_t)MTOT * FEA;           // 16,777,216
  ushort* B0 = (ushort*)d_ws;
  ushort* B1 = B0 + E;
  ushort* B2 = B1 + E;
  ushort* B3 = B2 + E;
  ushort* WB = B3 + E;                           // 6 x 512 x 512
  const size_t WE = (size_t)FEA * FEA;
  float* xt = out;                               // d_out as fp32 xt scratch

  dim3 gGemm(4, 256);                            // (N/128, M/128)

  // 1. xt = x + te (fp32 + bf16)
  add_fused<<<E / 8 / 256, 256, 0, stream>>>(x, te, xt, B0);
  // 2. weights -> bf16, transposed
  W6 w;
  w.s[0] = (const float*)d_in[2];  w.s[1] = (const float*)d_in[4];
  w.s[2] = (const float*)d_in[6];  w.s[3] = (const float*)d_in[8];
  w.s[4] = (const float*)d_in[10]; w.s[5] = (const float*)d_in[12];
  wconv<<<dim3(16, 16, 6), 256, 0, stream>>>(w, WB);
  // 3. q, k, v
  gemm_bf<0><<<gGemm, 256, 0, stream>>>(B0, WB + 0 * WE, bq, B1);
  gemm_bf<0><<<gGemm, 256, 0, stream>>>(B0, WB + 1 * WE, bk, B2);
  gemm_bf<0><<<gGemm, 256, 0, stream>>>(B0, WB + 2 * WE, bv, B3);
  // 4. attention (MFMA, in-place over q)
  attn_mfma<<<BB * NN * NH, 256, 0, stream>>>(B2, B3, B1);
  // 5. out1 = attn @ Wo + bo
  gemm_bf<0><<<gGemm, 256, 0, stream>>>(B1, WB + 3 * WE, bo, B2);
  // 6. y = LN(out1 + xt)  -> bf16
  ln_add<1, 0, 1><<<MTOT / 4, 256, 0, stream>>>(B2, xt, B0);
  // 7. h = relu(y @ W1 + b1)
  gemm_bf<1><<<gGemm, 256, 0, stream>>>(B0, WB + 4 * WE, b1, B3);
  // 8. h2 = h @ W2 + b2
  gemm_bf<0><<<gGemm, 256, 0, stream>>>(B3, WB + 5 * WE, b2, B1);
  // 9. out = LN(h2 + y) -> fp32
  ln_add<1, 1, 0><<<MTOT / 4, 256, 0, stream>>>(B1, B0, out);
}

// Round 6
// 454.167 us; speedup vs baseline: 3.5139x; 1.0151x over previous
//
#include <hip/hip_runtime.h>
#include <math.h>

typedef unsigned int uint;
typedef unsigned short ushort;

// Problem constants (reference: B=2, T=128, N=128, H=8, Dh=64, FEA=512)
#define FEA 512
#define NH 8
#define DH 64
#define BB 2
#define TT 128
#define NN 128
#define MTOT (BB*TT*NN)     // 32768 rows
#define SEG 16              // T / H
#define BETA 0.3f
#define LNEPS 1e-5f

typedef __attribute__((ext_vector_type(8))) _Float16 f16x8; // MFMA A/B frag (4 VGPRs)
typedef __attribute__((ext_vector_type(4))) float f32x4;    // MFMA C/D frag
typedef __attribute__((ext_vector_type(8))) short s16x8;    // 16B vector ld/st

static __device__ __forceinline__ ushort f2h(float x) {     // RTNE fp32->fp16
  _Float16 h = (_Float16)x;
  return __builtin_bit_cast(ushort, h);
}
static __device__ __forceinline__ float h2f(ushort u) {     // exact fp16->fp32
  return (float)__builtin_bit_cast(_Float16, u);
}

// ---------------------------------------------------------------------------
// xt = x + te -> fp16 only (serves as GEMM operand AND LN residual).
// ---------------------------------------------------------------------------
__global__ __launch_bounds__(256) void add_h(const float* __restrict__ x,
                                             const float* __restrict__ te,
                                             ushort* __restrict__ xth) {
  size_t i = ((size_t)blockIdx.x * 256 + threadIdx.x) * 8;
  float4 a0 = *(const float4*)&x[i];
  float4 a1 = *(const float4*)&x[i + 4];
  float4 b0 = *(const float4*)&te[i];
  float4 b1 = *(const float4*)&te[i + 4];
  s16x8 o;
  o[0]=(short)f2h(a0.x+b0.x); o[1]=(short)f2h(a0.y+b0.y);
  o[2]=(short)f2h(a0.z+b0.z); o[3]=(short)f2h(a0.w+b0.w);
  o[4]=(short)f2h(a1.x+b1.x); o[5]=(short)f2h(a1.y+b1.y);
  o[6]=(short)f2h(a1.z+b1.z); o[7]=(short)f2h(a1.w+b1.w);
  *(s16x8*)&xth[i] = o;
}

// ---------------------------------------------------------------------------
// Convert + transpose all 6 weights fp32 [k][n] -> fp16 WT [n][k].
// ---------------------------------------------------------------------------
struct W6 { const float* s[6]; };

__global__ __launch_bounds__(256) void wconv(W6 w, ushort* __restrict__ dst) {
  __shared__ float t[32][33];
  const float* W = w.s[blockIdx.z];
  ushort* WT = dst + (size_t)blockIdx.z * FEA * FEA;
  const int k0 = blockIdx.y * 32, n0 = blockIdx.x * 32;
  const int tx = threadIdx.x & 31, ty = threadIdx.x >> 5;   // 32 x 8
  #pragma unroll
  for (int i = 0; i < 4; ++i)
    t[ty + i * 8][tx] = W[(size_t)(k0 + ty + i * 8) * FEA + n0 + tx];
  __syncthreads();
  #pragma unroll
  for (int i = 0; i < 4; ++i)
    WT[(size_t)(n0 + ty + i * 8) * FEA + k0 + tx] = f2h(t[tx][ty + i * 8]);
}

// ---------------------------------------------------------------------------
// C[M,512](fp16) = A[M,512](fp16) @ WT^T + bias(f32), optional relu.
// 128x128 tile, BK=32, 256 threads (4 waves, 2x2), 4x4 16x16x32 frags/wave.
// SWAPPED operands: acc[i][j] = mfma(Wfrag[j], Afrag[i]) = C^T fragment,
// so lane (g,c) holds C[m=..+c][n=..+g*4+reg] -> 4 consecutive n per frag
// -> packed 8B stores (16 per thread vs 64 scalar 2B).
// Staging via global_load_lds width=16; LDS slots XOR-swizzled (both-sides).
// ---------------------------------------------------------------------------
template<int RELU>
__global__ __launch_bounds__(256) void gemm_h(const ushort* __restrict__ A,
                                              const ushort* __restrict__ WT,
                                              const float* __restrict__ bias,
                                              ushort* __restrict__ C) {
  __shared__ ushort As[128 * 32];
  __shared__ ushort Bs[128 * 32];
  const int tid = threadIdx.x;
  const int m0 = blockIdx.y * 128;
  const int n0 = blockIdx.x * 128;
  const int lane = tid & 63;
  const int wid = tid >> 6;
  const int wm = wid >> 1, wn = wid & 1;          // 2x2 wave grid (64x64 each)
  const int c = lane & 15, g = lane >> 4;         // frag row/col, k-group

  f32x4 acc[4][4] = {};                           // [m-frag][n-frag], D = C^T

  // Staging map: LDS slot i (16B) <- global (r = i>>2, kq = (i&3) ^ ((r>>1)&3))
  int r_[2], kq_[2];
  #pragma unroll
  for (int cc = 0; cc < 2; ++cc) {
    int i = cc * 256 + tid;
    r_[cc] = i >> 2;
    kq_[cc] = (i & 3) ^ ((r_[cc] >> 1) & 3);
  }

  for (int k0 = 0; k0 < 512; k0 += 32) {
    #pragma unroll
    for (int cc = 0; cc < 2; ++cc) {
      const ushort* ga = A  + (size_t)(m0 + r_[cc]) * 512 + k0 + kq_[cc] * 8;
      const ushort* gb = WT + (size_t)(n0 + r_[cc]) * 512 + k0 + kq_[cc] * 8;
      __builtin_amdgcn_global_load_lds(
          (const __attribute__((address_space(1))) void*)ga,
          (__attribute__((address_space(3))) void*)&As[(cc * 256 + tid) * 8], 16, 0, 0);
      __builtin_amdgcn_global_load_lds(
          (const __attribute__((address_space(1))) void*)gb,
          (__attribute__((address_space(3))) void*)&Bs[(cc * 256 + tid) * 8], 16, 0, 0);
    }
    __syncthreads();   // compiler drains vmcnt before s_barrier

    f16x8 af[4], bfr[4];
    #pragma unroll
    for (int s = 0; s < 4; ++s) {
      int ra = wm * 64 + s * 16 + c;
      int sa = ra * 4 + (g ^ ((ra >> 1) & 3));
      af[s] = *(const f16x8*)&As[sa * 8];
      int rb = wn * 64 + s * 16 + c;
      int sb = rb * 4 + (g ^ ((rb >> 1) & 3));
      bfr[s] = *(const f16x8*)&Bs[sb * 8];
    }
    #pragma unroll
    for (int i = 0; i < 4; ++i)
      #pragma unroll
      for (int j = 0; j < 4; ++j)
        acc[i][j] = __builtin_amdgcn_mfma_f32_16x16x32_f16(bfr[j], af[i], acc[i][j], 0, 0, 0);
    __syncthreads();
  }

  // Epilogue: lane (g,c) frag (i,j) holds C[m0+wm*64+i*16+c][n0+wn*64+j*16+g*4+reg]
  float4 bv4[4];
  #pragma unroll
  for (int j = 0; j < 4; ++j)
    bv4[j] = *(const float4*)&bias[n0 + wn * 64 + j * 16 + g * 4];
  #pragma unroll
  for (int i = 0; i < 4; ++i) {
    const size_t rb = (size_t)(m0 + wm * 64 + i * 16 + c) * 512;
    #pragma unroll
    for (int j = 0; j < 4; ++j) {
      const int nb = n0 + wn * 64 + j * 16 + g * 4;
      float o0 = acc[i][j][0] + bv4[j].x;
      float o1 = acc[i][j][1] + bv4[j].y;
      float o2 = acc[i][j][2] + bv4[j].z;
      float o3 = acc[i][j][3] + bv4[j].w;
      if (RELU) {
        o0 = fmaxf(o0, 0.f); o1 = fmaxf(o1, 0.f);
        o2 = fmaxf(o2, 0.f); o3 = fmaxf(o3, 0.f);
      }
      uint2 pk;
      pk.x = (uint)f2h(o0) | ((uint)f2h(o1) << 16);
      pk.y = (uint)f2h(o2) | ((uint)f2h(o3) << 16);
      *(uint2*)&C[rb + nb] = pk;
    }
  }
}

// ---------------------------------------------------------------------------
// MFMA attention (fp16). One block per (b,n,h), 4 waves; wave w owns q-rows
// [w*32, w*32+32), runs t-chunks 0..w (causal skip). Swapped QK^T ->
// lane-local softmax denom (2 shfl_xor). P -> fp16 -> per-wave swizzled LDS
// -> PV A-frags. K via global_load_lds (pre-swizzled source); V transposed
// in LDS with bank-spread slots. No main-loop barriers (P-buf per-wave).
// In-place over q.
// ---------------------------------------------------------------------------
__global__ __launch_bounds__(256) void attn_mfma(const ushort* __restrict__ kp,
                                                 const ushort* __restrict__ vp,
                                                 ushort* __restrict__ qo) {
  __shared__ ushort Ks[8192];      // 128t x 64d, 16B slots: slot(t,gs)=t*8+(gs^(t&7))
  __shared__ ushort Vt[8192];      // V^T 64d x 128t: slot(d,ts)=d*16+(ts^(d&7)^(d>>3))
  __shared__ ushort Pb[4][1024];   // per-wave P [32q][32t]: slot(qr,ts)=qr*4+(ts^(qr&3))
  __shared__ float  Lb[4][32];     // per-wave 1/l

  const int bid = blockIdx.x;
  const int h = bid & 7;
  const int n = (bid >> 3) & 127;
  const int b = bid >> 10;
  const int tid = threadIdx.x;
  const int lane = tid & 63;
  const int w = tid >> 6;
  const int g = lane >> 4, c = lane & 15;
  const size_t tstride = (size_t)NN * FEA;
  const size_t base = ((size_t)b * TT * NN + n) * FEA + (size_t)h * DH;

  #pragma unroll
  for (int it = 0; it < 4; ++it) {
    int i = it * 256 + tid;
    int t = i >> 3;
    int gd = (i & 7) ^ (t & 7);
    const ushort* gk = kp + base + (size_t)t * tstride + gd * 8;
    __builtin_amdgcn_global_load_lds(
        (const __attribute__((address_space(1))) void*)gk,
        (__attribute__((address_space(3))) void*)&Ks[i * 8], 16, 0, 0);
  }
  #pragma unroll
  for (int it = 0; it < 4; ++it) {
    int j = it * 256 + tid;
    int t = j >> 3, d0 = (j & 7) * 8;
    s16x8 vv = *(const s16x8*)&vp[base + (size_t)t * tstride + d0];
    #pragma unroll
    for (int jj = 0; jj < 8; ++jj) {
      int d = d0 + jj;
      int slot = d * 16 + ((t >> 3) ^ (d & 7) ^ (d >> 3));
      Vt[slot * 8 + (t & 7)] = (ushort)vv[jj];
    }
  }
  const int qb = w * 32;
  f16x8 Qf[2][2];
  #pragma unroll
  for (int qt = 0; qt < 2; ++qt)
    #pragma unroll
    for (int kf = 0; kf < 2; ++kf)
      Qf[qt][kf] = *(const f16x8*)
          &qo[base + (size_t)(qb + qt * 16 + c) * tstride + kf * 32 + g * 8];
  __syncthreads();   // drains vmcnt (global_load_lds) + lgkm

  const int fs = h * SEG;
  const int fe = (h == NH - 1) ? TT : fs + SEG;

  f32x4 Oa[2][4];
  #pragma unroll
  for (int qt = 0; qt < 2; ++qt)
    #pragma unroll
    for (int dt = 0; dt < 4; ++dt)
      Oa[qt][dt] = (f32x4){0.f, 0.f, 0.f, 0.f};
  float lsum[2] = {0.f, 0.f};

  for (int ch = 0; ch <= w; ++ch) {
    const int tc = ch * 32;
    f32x4 sf[2][2];
    #pragma unroll
    for (int tt2 = 0; tt2 < 2; ++tt2) {
      f16x8 Kf[2];
      #pragma unroll
      for (int kf = 0; kf < 2; ++kf) {
        int t = tc + tt2 * 16 + c;                    // A-frag row = c
        int slot = t * 8 + ((kf * 4 + g) ^ (c & 7));  // t&7 == c&7
        Kf[kf] = *(const f16x8*)&Ks[slot * 8];
      }
      #pragma unroll
      for (int qt = 0; qt < 2; ++qt) {
        f32x4 s = (f32x4){0.f, 0.f, 0.f, 0.f};
        s = __builtin_amdgcn_mfma_f32_16x16x32_f16(Kf[0], Qf[qt][0], s, 0, 0, 0);
        s = __builtin_amdgcn_mfma_f32_16x16x32_f16(Kf[1], Qf[qt][1], s, 0, 0, 0);
        sf[tt2][qt] = s;
      }
    }
    #pragma unroll
    for (int tt2 = 0; tt2 < 2; ++tt2) {
      #pragma unroll
      for (int qt = 0; qt < 2; ++qt) {
        const int q = qb + qt * 16 + c;               // D col = q
        const int qr = qt * 16 + c;                   // P-buf row
        #pragma unroll
        for (int pr = 0; pr < 2; ++pr) {
          float pv[2];
          #pragma unroll
          for (int rr = 0; rr < 2; ++rr) {
            int reg = pr * 2 + rr;
            int t = tc + tt2 * 16 + g * 4 + reg;      // D row = t
            float mult = (t >= fs && t < fe) ? 0.125f : 0.125f * BETA;
            float p = __expf(sf[tt2][qt][reg] * mult);
            p = (t <= q) ? p : 0.f;
            pv[rr] = p;
            lsum[qt] += p;
          }
          uint pk = (uint)f2h(pv[0]) | ((uint)f2h(pv[1]) << 16);
          int tl = tt2 * 16 + g * 4 + pr * 2;
          int slot = qr * 4 + ((tl >> 3) ^ (qr & 3));
          *(uint*)&Pb[w][slot * 8 + (tl & 7)] = pk;
        }
      }
    }
    f16x8 Vf[4];
    #pragma unroll
    for (int dt = 0; dt < 4; ++dt) {
      int d = dt * 16 + c;                            // B-frag col = d
      int slot = d * 16 + ((((tc >> 3)) + g) ^ (d & 7) ^ (d >> 3));
      Vf[dt] = *(const f16x8*)&Vt[slot * 8];
    }
    #pragma unroll
    for (int qt = 0; qt < 2; ++qt) {
      int qr = qt * 16 + c;                           // A-frag row = q
      int slot = qr * 4 + (g ^ (qr & 3));
      f16x8 Pa = *(const f16x8*)&Pb[w][slot * 8];
      #pragma unroll
      for (int dt = 0; dt < 4; ++dt)
        Oa[qt][dt] = __builtin_amdgcn_mfma_f32_16x16x32_f16(Pa, Vf[dt], Oa[qt][dt], 0, 0, 0);
    }
  }

  #pragma unroll
  for (int qt = 0; qt < 2; ++qt) {
    lsum[qt] += __shfl_xor(lsum[qt], 16, 64);
    lsum[qt] += __shfl_xor(lsum[qt], 32, 64);
  }
  if (g == 0) {
    Lb[w][c]      = 1.0f / lsum[0];
    Lb[w][16 + c] = 1.0f / lsum[1];
  }
  #pragma unroll
  for (int qt = 0; qt < 2; ++qt) {
    f32x4 linv = *(const f32x4*)&Lb[w][qt * 16 + g * 4];
    #pragma unroll
    for (int dt = 0; dt < 4; ++dt) {
      #pragma unroll
      for (int reg = 0; reg < 4; ++reg) {
        int q = qb + qt * 16 + g * 4 + reg;           // D row = q
        qo[base + (size_t)q * tstride + dt * 16 + c] = f2h(Oa[qt][dt][reg] * linv[reg]);
      }
    }
  }
}

// ---------------------------------------------------------------------------
// y = LayerNorm(a + r) over last dim 512; one wave/row, 4 rows/block.
// AH/RH/OH: fp16 (1) vs fp32 (0) per tensor. In-place safe (own-row only).
// ---------------------------------------------------------------------------
template<int AH, int RH, int OH>
__global__ __launch_bounds__(256) void ln_add(const void* __restrict__ a_,
                                              const void* __restrict__ r_,
                                              void* __restrict__ y_) {
  const int lane = threadIdx.x & 63;
  const int w = threadIdx.x >> 6;
  const size_t row = (size_t)blockIdx.x * 4 + w;
  const size_t off = row * FEA + (size_t)lane * 8;
  float ua[8], ur[8], u[8];
  if (AH) {
    s16x8 v = *(const s16x8*)&((const ushort*)a_)[off];
    #pragma unroll
    for (int j = 0; j < 8; ++j) ua[j] = h2f((ushort)v[j]);
  } else {
    float4 v0 = *(const float4*)&((const float*)a_)[off];
    float4 v1 = *(const float4*)&((const float*)a_)[off + 4];
    ua[0]=v0.x; ua[1]=v0.y; ua[2]=v0.z; ua[3]=v0.w;
    ua[4]=v1.x; ua[5]=v1.y; ua[6]=v1.z; ua[7]=v1.w;
  }
  if (RH) {
    s16x8 v = *(const s16x8*)&((const ushort*)r_)[off];
    #pragma unroll
    for (int j = 0; j < 8; ++j) ur[j] = h2f((ushort)v[j]);
  } else {
    float4 v0 = *(const float4*)&((const float*)r_)[off];
    float4 v1 = *(const float4*)&((const float*)r_)[off + 4];
    ur[0]=v0.x; ur[1]=v0.y; ur[2]=v0.z; ur[3]=v0.w;
    ur[4]=v1.x; ur[5]=v1.y; ur[6]=v1.z; ur[7]=v1.w;
  }
  float sum = 0.f, sq = 0.f;
  #pragma unroll
  for (int j = 0; j < 8; ++j) {
    u[j] = ua[j] + ur[j];
    sum += u[j];
    sq = fmaf(u[j], u[j], sq);
  }
  #pragma unroll
  for (int m = 1; m < 64; m <<= 1) {
    sum += __shfl_xor(sum, m, 64);
    sq  += __shfl_xor(sq,  m, 64);
  }
  const float mean = sum * (1.0f / FEA);
  const float var = sq * (1.0f / FEA) - mean * mean;
  const float rstd = rsqrtf(var + LNEPS);
  if (OH) {
    s16x8 o;
    #pragma unroll
    for (int j = 0; j < 8; ++j) o[j] = (short)f2h((u[j] - mean) * rstd);
    *(s16x8*)&((ushort*)y_)[off] = o;
  } else {
    float4 o0, o1;
    o0.x=(u[0]-mean)*rstd; o0.y=(u[1]-mean)*rstd; o0.z=(u[2]-mean)*rstd; o0.w=(u[3]-mean)*rstd;
    o1.x=(u[4]-mean)*rstd; o1.y=(u[5]-mean)*rstd; o1.z=(u[6]-mean)*rstd; o1.w=(u[7]-mean)*rstd;
    *(float4*)&((float*)y_)[off] = o0;
    *(float4*)&((float*)y_)[off + 4] = o1;
  }
}

// ---------------------------------------------------------------------------
// Orchestration. ws (131 MiB): B0..B3 fp16 buffers (32 MiB each) + WB (3 MiB).
//   B0: xt_h -> y (step 6, in-place residual read)
//   B1: q -> attnout (in place) -> h2 (step 8)
//   B2: k -> out1 (step 5)
//   B3: v -> h (step 7)
// ---------------------------------------------------------------------------
extern "C" void kernel_launch(void* const* d_in, const int* in_sizes, int n_in,
                              void* d_out, int out_size, void* d_ws, size_t ws_size,
                              hipStream_t stream) {
  const float* x  = (const float*)d_in[0];
  const float* te = (const float*)d_in[1];
  const float* bq = (const float*)d_in[3];
  const float* bk = (const float*)d_in[5];
  const float* bv = (const float*)d_in[7];
  const float* bo = (const float*)d_in[9];
  const float* b1 = (const float*)d_in[11];
  const float* b2 = (const float*)d_in[13];
  float* out = (float*)d_out;

  const size_t E = (size_t)MTOT * FEA;           // 16,777,216
  ushort* B0 = (ushort*)d_ws;
  ushort* B1 = B0 + E;
  ushort* B2 = B1 + E;
  ushort* B3 = B2 + E;
  ushort* WB = B3 + E;                           // 6 x 512 x 512
  const size_t WE = (size_t)FEA * FEA;

  dim3 gGemm(4, 256);                            // (N/128, M/128)

  // 1. xt = x + te -> fp16
  add_h<<<E / 8 / 256, 256, 0, stream>>>(x, te, B0);
  // 2. weights -> fp16, transposed
  W6 w;
  w.s[0] = (const float*)d_in[2];  w.s[1] = (const float*)d_in[4];
  w.s[2] = (const float*)d_in[6];  w.s[3] = (const float*)d_in[8];
  w.s[4] = (const float*)d_in[10]; w.s[5] = (const float*)d_in[12];
  wconv<<<dim3(16, 16, 6), 256, 0, stream>>>(w, WB);
  // 3. q, k, v
  gemm_h<0><<<gGemm, 256, 0, stream>>>(B0, WB + 0 * WE, bq, B1);
  gemm_h<0><<<gGemm, 256, 0, stream>>>(B0, WB + 1 * WE, bk, B2);
  gemm_h<0><<<gGemm, 256, 0, stream>>>(B0, WB + 2 * WE, bv, B3);
  // 4. attention (MFMA, in-place over q)
  attn_mfma<<<BB * NN * NH, 256, 0, stream>>>(B2, B3, B1);
  // 5. out1 = attn @ Wo + bo
  gemm_h<0><<<gGemm, 256, 0, stream>>>(B1, WB + 3 * WE, bo, B2);
  // 6. y = LN(out1 + xt) -> fp16, in-place over B0
  ln_add<1, 1, 1><<<MTOT / 4, 256, 0, stream>>>(B2, B0, B0);
  // 7. h = relu(y @ W1 + b1)
  gemm_h<1><<<gGemm, 256, 0, stream>>>(B0, WB + 4 * WE, b1, B3);
  // 8. h2 = h @ W2 + b2
  gemm_h<0><<<gGemm, 256, 0, stream>>>(B3, WB + 5 * WE, b2, B1);
  // 9. out = LN(h2 + y) -> fp32
  ln_add<1, 1, 0><<<MTOT / 4, 256, 0, stream>>>(B1, B0, out);
}

// Round 7
// 450.127 us; speedup vs baseline: 3.5455x; 1.0090x over previous
//
#include <hip/hip_runtime.h>
#include <math.h>

typedef unsigned int uint;
typedef unsigned short ushort;

// Problem constants (reference: B=2, T=128, N=128, H=8, Dh=64, FEA=512)
#define FEA 512
#define NH 8
#define DH 64
#define BB 2
#define TT 128
#define NN 128
#define MTOT (BB*TT*NN)     // 32768 rows
#define SEG 16              // T / H
#define BETA 0.3f
#define LNEPS 1e-5f

typedef __attribute__((ext_vector_type(8))) _Float16 f16x8; // MFMA A/B frag (4 VGPRs)
typedef __attribute__((ext_vector_type(4))) float f32x4;    // MFMA C/D frag
typedef __attribute__((ext_vector_type(8))) short s16x8;    // 16B vector ld/st

static __device__ __forceinline__ ushort f2h(float x) {     // RTNE fp32->fp16
  _Float16 h = (_Float16)x;
  return __builtin_bit_cast(ushort, h);
}
static __device__ __forceinline__ float h2f(ushort u) {     // exact fp16->fp32
  return (float)__builtin_bit_cast(_Float16, u);
}

// ---------------------------------------------------------------------------
// xt = x + te -> fp16 only (serves as GEMM operand AND LN residual).
// (unchanged from round 6 — measured 52 µs; control dispatch)
// ---------------------------------------------------------------------------
__global__ __launch_bounds__(256) void add_h(const float* __restrict__ x,
                                             const float* __restrict__ te,
                                             ushort* __restrict__ xth) {
  size_t i = ((size_t)blockIdx.x * 256 + threadIdx.x) * 8;
  float4 a0 = *(const float4*)&x[i];
  float4 a1 = *(const float4*)&x[i + 4];
  float4 b0 = *(const float4*)&te[i];
  float4 b1 = *(const float4*)&te[i + 4];
  s16x8 o;
  o[0]=(short)f2h(a0.x+b0.x); o[1]=(short)f2h(a0.y+b0.y);
  o[2]=(short)f2h(a0.z+b0.z); o[3]=(short)f2h(a0.w+b0.w);
  o[4]=(short)f2h(a1.x+b1.x); o[5]=(short)f2h(a1.y+b1.y);
  o[6]=(short)f2h(a1.z+b1.z); o[7]=(short)f2h(a1.w+b1.w);
  *(s16x8*)&xth[i] = o;
}

// ---------------------------------------------------------------------------
// Convert + transpose all 6 weights fp32 [k][n] -> fp16 WT [n][k].
// ---------------------------------------------------------------------------
struct W6 { const float* s[6]; };

__global__ __launch_bounds__(256) void wconv(W6 w, ushort* __restrict__ dst) {
  __shared__ float t[32][33];
  const float* W = w.s[blockIdx.z];
  ushort* WT = dst + (size_t)blockIdx.z * FEA * FEA;
  const int k0 = blockIdx.y * 32, n0 = blockIdx.x * 32;
  const int tx = threadIdx.x & 31, ty = threadIdx.x >> 5;   // 32 x 8
  #pragma unroll
  for (int i = 0; i < 4; ++i)
    t[ty + i * 8][tx] = W[(size_t)(k0 + ty + i * 8) * FEA + n0 + tx];
  __syncthreads();
  #pragma unroll
  for (int i = 0; i < 4; ++i)
    WT[(size_t)(n0 + ty + i * 8) * FEA + k0 + tx] = f2h(t[tx][ty + i * 8]);
}

// ---------------------------------------------------------------------------
// C[M,512](fp16) = A[M,512](fp16) @ WT^T + bias(f32), optional relu.
// 128x128 tile, BK=32, 256 threads (4 waves 2x2), 4x4 16x16x32 frags/wave.
// NEW: 2-phase double-buffered K-loop (T3 minimum recipe): issue next-tile
// global_load_lds BEFORE computing current tile; ONE barrier per K-step
// (17 total vs 32). WAR-safe: ds_reads are lgkm-drained before MFMA issue,
// which precedes the barrier; compiler's vmcnt(0)-before-barrier guarantees
// next tile is resident after the barrier.
// NW=3: fused QKV — blockIdx.x>>2 selects weight/bias/out; n0=(bx&3)*128.
// Swapped-operand MFMA epilogue (C^T frags -> packed 8B stores), unchanged.
// ---------------------------------------------------------------------------
struct GArgs {
  const ushort* wt[3];
  const float* bias[3];
  ushort* out[3];
};

template<int RELU, int NW>
__global__ __launch_bounds__(256) void gemm_h(const ushort* __restrict__ A, GArgs p) {
  __shared__ ushort As[2][4096];
  __shared__ ushort Bs[2][4096];
  const int tid = threadIdx.x;
  const int m0 = blockIdx.y * 128;
  const int wsel = (NW == 3) ? (blockIdx.x >> 2) : 0;
  const int n0 = ((NW == 3) ? (blockIdx.x & 3) : blockIdx.x) * 128;
  const ushort* __restrict__ WT = p.wt[wsel];
  const float*  __restrict__ bias = p.bias[wsel];
  ushort* __restrict__ C = p.out[wsel];
  const int lane = tid & 63;
  const int wid = tid >> 6;
  const int wm = wid >> 1, wn = wid & 1;          // 2x2 wave grid (64x64 each)
  const int c = lane & 15, g = lane >> 4;         // frag row, k-group

  f32x4 acc[4][4] = {};                           // [m-frag][n-frag], D = C^T

  // Staging map: LDS slot i (16B) <- global (r = i>>2, kq = (i&3) ^ ((r>>1)&3))
  int r_[2], kq_[2];
  #pragma unroll
  for (int cc = 0; cc < 2; ++cc) {
    int i = cc * 256 + tid;
    r_[cc] = i >> 2;
    kq_[cc] = (i & 3) ^ ((r_[cc] >> 1) & 3);
  }

  auto stage = [&](int buf, int k0) {
    #pragma unroll
    for (int cc = 0; cc < 2; ++cc) {
      const ushort* ga = A  + (size_t)(m0 + r_[cc]) * 512 + k0 + kq_[cc] * 8;
      const ushort* gb = WT + (size_t)(n0 + r_[cc]) * 512 + k0 + kq_[cc] * 8;
      __builtin_amdgcn_global_load_lds(
          (const __attribute__((address_space(1))) void*)ga,
          (__attribute__((address_space(3))) void*)&As[buf][(cc * 256 + tid) * 8], 16, 0, 0);
      __builtin_amdgcn_global_load_lds(
          (const __attribute__((address_space(1))) void*)gb,
          (__attribute__((address_space(3))) void*)&Bs[buf][(cc * 256 + tid) * 8], 16, 0, 0);
    }
  };

  stage(0, 0);
  __syncthreads();                                // buf0 resident
  int cur = 0;
  for (int t = 0; t < 16; ++t) {
    if (t < 15) stage(cur ^ 1, (t + 1) * 32);     // prefetch next tile

    f16x8 af[4], bfr[4];
    #pragma unroll
    for (int s = 0; s < 4; ++s) {
      int ra = wm * 64 + s * 16 + c;
      int sa = ra * 4 + (g ^ ((ra >> 1) & 3));
      af[s] = *(const f16x8*)&As[cur][sa * 8];
      int rb = wn * 64 + s * 16 + c;
      int sb = rb * 4 + (g ^ ((rb >> 1) & 3));
      bfr[s] = *(const f16x8*)&Bs[cur][sb * 8];
    }
    #pragma unroll
    for (int i = 0; i < 4; ++i)
      #pragma unroll
      for (int j = 0; j < 4; ++j)
        acc[i][j] = __builtin_amdgcn_mfma_f32_16x16x32_f16(bfr[j], af[i], acc[i][j], 0, 0, 0);

    __syncthreads();                              // drains vmcnt: next tile ready
    cur ^= 1;
  }

  // Epilogue: lane (g,c) frag (i,j) holds C[m0+wm*64+i*16+c][n0+wn*64+j*16+g*4+reg]
  float4 bv4[4];
  #pragma unroll
  for (int j = 0; j < 4; ++j)
    bv4[j] = *(const float4*)&bias[n0 + wn * 64 + j * 16 + g * 4];
  #pragma unroll
  for (int i = 0; i < 4; ++i) {
    const size_t rb = (size_t)(m0 + wm * 64 + i * 16 + c) * 512;
    #pragma unroll
    for (int j = 0; j < 4; ++j) {
      const int nb = n0 + wn * 64 + j * 16 + g * 4;
      float o0 = acc[i][j][0] + bv4[j].x;
      float o1 = acc[i][j][1] + bv4[j].y;
      float o2 = acc[i][j][2] + bv4[j].z;
      float o3 = acc[i][j][3] + bv4[j].w;
      if (RELU) {
        o0 = fmaxf(o0, 0.f); o1 = fmaxf(o1, 0.f);
        o2 = fmaxf(o2, 0.f); o3 = fmaxf(o3, 0.f);
      }
      uint2 pk;
      pk.x = (uint)f2h(o0) | ((uint)f2h(o1) << 16);
      pk.y = (uint)f2h(o2) | ((uint)f2h(o3) << 16);
      *(uint2*)&C[rb + nb] = pk;
    }
  }
}

// ---------------------------------------------------------------------------
// MFMA attention (fp16). Unchanged from round 6 (measured fast, <51 µs).
// ---------------------------------------------------------------------------
__global__ __launch_bounds__(256) void attn_mfma(const ushort* __restrict__ kp,
                                                 const ushort* __restrict__ vp,
                                                 ushort* __restrict__ qo) {
  __shared__ ushort Ks[8192];      // 128t x 64d, 16B slots: slot(t,gs)=t*8+(gs^(t&7))
  __shared__ ushort Vt[8192];      // V^T 64d x 128t: slot(d,ts)=d*16+(ts^(d&7)^(d>>3))
  __shared__ ushort Pb[4][1024];   // per-wave P [32q][32t]: slot(qr,ts)=qr*4+(ts^(qr&3))
  __shared__ float  Lb[4][32];     // per-wave 1/l

  const int bid = blockIdx.x;
  const int h = bid & 7;
  const int n = (bid >> 3) & 127;
  const int b = bid >> 10;
  const int tid = threadIdx.x;
  const int lane = tid & 63;
  const int w = tid >> 6;
  const int g = lane >> 4, c = lane & 15;
  const size_t tstride = (size_t)NN * FEA;
  const size_t base = ((size_t)b * TT * NN + n) * FEA + (size_t)h * DH;

  #pragma unroll
  for (int it = 0; it < 4; ++it) {
    int i = it * 256 + tid;
    int t = i >> 3;
    int gd = (i & 7) ^ (t & 7);
    const ushort* gk = kp + base + (size_t)t * tstride + gd * 8;
    __builtin_amdgcn_global_load_lds(
        (const __attribute__((address_space(1))) void*)gk,
        (__attribute__((address_space(3))) void*)&Ks[i * 8], 16, 0, 0);
  }
  #pragma unroll
  for (int it = 0; it < 4; ++it) {
    int j = it * 256 + tid;
    int t = j >> 3, d0 = (j & 7) * 8;
    s16x8 vv = *(const s16x8*)&vp[base + (size_t)t * tstride + d0];
    #pragma unroll
    for (int jj = 0; jj < 8; ++jj) {
      int d = d0 + jj;
      int slot = d * 16 + ((t >> 3) ^ (d & 7) ^ (d >> 3));
      Vt[slot * 8 + (t & 7)] = (ushort)vv[jj];
    }
  }
  const int qb = w * 32;
  f16x8 Qf[2][2];
  #pragma unroll
  for (int qt = 0; qt < 2; ++qt)
    #pragma unroll
    for (int kf = 0; kf < 2; ++kf)
      Qf[qt][kf] = *(const f16x8*)
          &qo[base + (size_t)(qb + qt * 16 + c) * tstride + kf * 32 + g * 8];
  __syncthreads();   // drains vmcnt (global_load_lds) + lgkm

  const int fs = h * SEG;
  const int fe = (h == NH - 1) ? TT : fs + SEG;

  f32x4 Oa[2][4];
  #pragma unroll
  for (int qt = 0; qt < 2; ++qt)
    #pragma unroll
    for (int dt = 0; dt < 4; ++dt)
      Oa[qt][dt] = (f32x4){0.f, 0.f, 0.f, 0.f};
  float lsum[2] = {0.f, 0.f};

  for (int ch = 0; ch <= w; ++ch) {
    const int tc = ch * 32;
    f32x4 sf[2][2];
    #pragma unroll
    for (int tt2 = 0; tt2 < 2; ++tt2) {
      f16x8 Kf[2];
      #pragma unroll
      for (int kf = 0; kf < 2; ++kf) {
        int t = tc + tt2 * 16 + c;                    // A-frag row = c
        int slot = t * 8 + ((kf * 4 + g) ^ (c & 7));  // t&7 == c&7
        Kf[kf] = *(const f16x8*)&Ks[slot * 8];
      }
      #pragma unroll
      for (int qt = 0; qt < 2; ++qt) {
        f32x4 s = (f32x4){0.f, 0.f, 0.f, 0.f};
        s = __builtin_amdgcn_mfma_f32_16x16x32_f16(Kf[0], Qf[qt][0], s, 0, 0, 0);
        s = __builtin_amdgcn_mfma_f32_16x16x32_f16(Kf[1], Qf[qt][1], s, 0, 0, 0);
        sf[tt2][qt] = s;
      }
    }
    #pragma unroll
    for (int tt2 = 0; tt2 < 2; ++tt2) {
      #pragma unroll
      for (int qt = 0; qt < 2; ++qt) {
        const int q = qb + qt * 16 + c;               // D col = q
        const int qr = qt * 16 + c;                   // P-buf row
        #pragma unroll
        for (int pr = 0; pr < 2; ++pr) {
          float pv[2];
          #pragma unroll
          for (int rr = 0; rr < 2; ++rr) {
            int reg = pr * 2 + rr;
            int t = tc + tt2 * 16 + g * 4 + reg;      // D row = t
            float mult = (t >= fs && t < fe) ? 0.125f : 0.125f * BETA;
            float p = __expf(sf[tt2][qt][reg] * mult);
            p = (t <= q) ? p : 0.f;
            pv[rr] = p;
            lsum[qt] += p;
          }
          uint pk = (uint)f2h(pv[0]) | ((uint)f2h(pv[1]) << 16);
          int tl = tt2 * 16 + g * 4 + pr * 2;
          int slot = qr * 4 + ((tl >> 3) ^ (qr & 3));
          *(uint*)&Pb[w][slot * 8 + (tl & 7)] = pk;
        }
      }
    }
    f16x8 Vf[4];
    #pragma unroll
    for (int dt = 0; dt < 4; ++dt) {
      int d = dt * 16 + c;                            // B-frag col = d
      int slot = d * 16 + ((((tc >> 3)) + g) ^ (d & 7) ^ (d >> 3));
      Vf[dt] = *(const f16x8*)&Vt[slot * 8];
    }
    #pragma unroll
    for (int qt = 0; qt < 2; ++qt) {
      int qr = qt * 16 + c;                           // A-frag row = q
      int slot = qr * 4 + (g ^ (qr & 3));
      f16x8 Pa = *(const f16x8*)&Pb[w][slot * 8];
      #pragma unroll
      for (int dt = 0; dt < 4; ++dt)
        Oa[qt][dt] = __builtin_amdgcn_mfma_f32_16x16x32_f16(Pa, Vf[dt], Oa[qt][dt], 0, 0, 0);
    }
  }

  #pragma unroll
  for (int qt = 0; qt < 2; ++qt) {
    lsum[qt] += __shfl_xor(lsum[qt], 16, 64);
    lsum[qt] += __shfl_xor(lsum[qt], 32, 64);
  }
  if (g == 0) {
    Lb[w][c]      = 1.0f / lsum[0];
    Lb[w][16 + c] = 1.0f / lsum[1];
  }
  #pragma unroll
  for (int qt = 0; qt < 2; ++qt) {
    f32x4 linv = *(const f32x4*)&Lb[w][qt * 16 + g * 4];
    #pragma unroll
    for (int dt = 0; dt < 4; ++dt) {
      #pragma unroll
      for (int reg = 0; reg < 4; ++reg) {
        int q = qb + qt * 16 + g * 4 + reg;           // D row = q
        qo[base + (size_t)q * tstride + dt * 16 + c] = f2h(Oa[qt][dt][reg] * linv[reg]);
      }
    }
  }
}

// ---------------------------------------------------------------------------
// y = LayerNorm(a + r) over last dim 512; one wave/row, 4 rows/block.
// AH/RH/OH: fp16 (1) vs fp32 (0) per tensor. In-place safe (own-row only).
// ---------------------------------------------------------------------------
template<int AH, int RH, int OH>
__global__ __launch_bounds__(256) void ln_add(const void* __restrict__ a_,
                                              const void* __restrict__ r_,
                                              void* __restrict__ y_) {
  const int lane = threadIdx.x & 63;
  const int w = threadIdx.x >> 6;
  const size_t row = (size_t)blockIdx.x * 4 + w;
  const size_t off = row * FEA + (size_t)lane * 8;
  float ua[8], ur[8], u[8];
  if (AH) {
    s16x8 v = *(const s16x8*)&((const ushort*)a_)[off];
    #pragma unroll
    for (int j = 0; j < 8; ++j) ua[j] = h2f((ushort)v[j]);
  } else {
    float4 v0 = *(const float4*)&((const float*)a_)[off];
    float4 v1 = *(const float4*)&((const float*)a_)[off + 4];
    ua[0]=v0.x; ua[1]=v0.y; ua[2]=v0.z; ua[3]=v0.w;
    ua[4]=v1.x; ua[5]=v1.y; ua[6]=v1.z; ua[7]=v1.w;
  }
  if (RH) {
    s16x8 v = *(const s16x8*)&((const ushort*)r_)[off];
    #pragma unroll
    for (int j = 0; j < 8; ++j) ur[j] = h2f((ushort)v[j]);
  } else {
    float4 v0 = *(const float4*)&((const float*)r_)[off];
    float4 v1 = *(const float4*)&((const float*)r_)[off + 4];
    ur[0]=v0.x; ur[1]=v0.y; ur[2]=v0.z; ur[3]=v0.w;
    ur[4]=v1.x; ur[5]=v1.y; ur[6]=v1.z; ur[7]=v1.w;
  }
  float sum = 0.f, sq = 0.f;
  #pragma unroll
  for (int j = 0; j < 8; ++j) {
    u[j] = ua[j] + ur[j];
    sum += u[j];
    sq = fmaf(u[j], u[j], sq);
  }
  #pragma unroll
  for (int m = 1; m < 64; m <<= 1) {
    sum += __shfl_xor(sum, m, 64);
    sq  += __shfl_xor(sq,  m, 64);
  }
  const float mean = sum * (1.0f / FEA);
  const float var = sq * (1.0f / FEA) - mean * mean;
  const float rstd = rsqrtf(var + LNEPS);
  if (OH) {
    s16x8 o;
    #pragma unroll
    for (int j = 0; j < 8; ++j) o[j] = (short)f2h((u[j] - mean) * rstd);
    *(s16x8*)&((ushort*)y_)[off] = o;
  } else {
    float4 o0, o1;
    o0.x=(u[0]-mean)*rstd; o0.y=(u[1]-mean)*rstd; o0.z=(u[2]-mean)*rstd; o0.w=(u[3]-mean)*rstd;
    o1.x=(u[4]-mean)*rstd; o1.y=(u[5]-mean)*rstd; o1.z=(u[6]-mean)*rstd; o1.w=(u[7]-mean)*rstd;
    *(float4*)&((float*)y_)[off] = o0;
    *(float4*)&((float*)y_)[off + 4] = o1;
  }
}

// ---------------------------------------------------------------------------
// Orchestration. ws (131 MiB): B0..B3 fp16 buffers (32 MiB each) + WB (3 MiB).
//   B0: xt_h -> y (step 6, in-place residual read)
//   B1: q -> attnout (in place) -> h2 (step 8)
//   B2: k -> out1 (step 5)
//   B3: v -> h (step 7)
// ---------------------------------------------------------------------------
extern "C" void kernel_launch(void* const* d_in, const int* in_sizes, int n_in,
                              void* d_out, int out_size, void* d_ws, size_t ws_size,
                              hipStream_t stream) {
  const float* x  = (const float*)d_in[0];
  const float* te = (const float*)d_in[1];
  const float* bq = (const float*)d_in[3];
  const float* bk = (const float*)d_in[5];
  const float* bv = (const float*)d_in[7];
  const float* bo = (const float*)d_in[9];
  const float* b1 = (const float*)d_in[11];
  const float* b2 = (const float*)d_in[13];
  float* out = (float*)d_out;

  const size_t E = (size_t)MTOT * FEA;           // 16,777,216
  ushort* B0 = (ushort*)d_ws;
  ushort* B1 = B0 + E;
  ushort* B2 = B1 + E;
  ushort* B3 = B2 + E;
  ushort* WB = B3 + E;                           // 6 x 512 x 512
  const size_t WE = (size_t)FEA * FEA;

  // 1. xt = x + te -> fp16
  add_h<<<E / 8 / 256, 256, 0, stream>>>(x, te, B0);
  // 2. weights -> fp16, transposed
  W6 w;
  w.s[0] = (const float*)d_in[2];  w.s[1] = (const float*)d_in[4];
  w.s[2] = (const float*)d_in[6];  w.s[3] = (const float*)d_in[8];
  w.s[4] = (const float*)d_in[10]; w.s[5] = (const float*)d_in[12];
  wconv<<<dim3(16, 16, 6), 256, 0, stream>>>(w, WB);
  // 3. fused q,k,v GEMM (grid x: 0-3 -> q, 4-7 -> k, 8-11 -> v)
  GArgs gqkv;
  gqkv.wt[0] = WB;          gqkv.bias[0] = bq; gqkv.out[0] = B1;
  gqkv.wt[1] = WB + WE;     gqkv.bias[1] = bk; gqkv.out[1] = B2;
  gqkv.wt[2] = WB + 2 * WE; gqkv.bias[2] = bv; gqkv.out[2] = B3;
  gemm_h<0, 3><<<dim3(12, 256), 256, 0, stream>>>(B0, gqkv);
  // 4. attention (MFMA, in-place over q)
  attn_mfma<<<BB * NN * NH, 256, 0, stream>>>(B2, B3, B1);
  // 5. out1 = attn @ Wo + bo
  GArgs go = {};
  go.wt[0] = WB + 3 * WE; go.bias[0] = bo; go.out[0] = B2;
  gemm_h<0, 1><<<dim3(4, 256), 256, 0, stream>>>(B1, go);
  // 6. y = LN(out1 + xt) -> fp16, in-place over B0
  ln_add<1, 1, 1><<<MTOT / 4, 256, 0, stream>>>(B2, B0, B0);
  // 7. h = relu(y @ W1 + b1)
  GArgs g1 = {};
  g1.wt[0] = WB + 4 * WE; g1.bias[0] = b1; g1.out[0] = B3;
  gemm_h<1, 1><<<dim3(4, 256), 256, 0, stream>>>(B0, g1);
  // 8. h2 = h @ W2 + b2
  GArgs g2 = {};
  g2.wt[0] = WB + 5 * WE; g2.bias[0] = b2; g2.out[0] = B1;
  gemm_h<0, 1><<<dim3(4, 256), 256, 0, stream>>>(B3, g2);
  // 9. out = LN(h2 + y) -> fp32
  ln_add<1, 1, 0><<<MTOT / 4, 256, 0, stream>>>(B1, B0, out);
}

// Round 8
// 431.440 us; speedup vs baseline: 3.6990x; 1.0433x over previous
//
#include <hip/hip_runtime.h>
#include <math.h>

typedef unsigned int uint;
typedef unsigned short ushort;

// Problem constants (reference: B=2, T=128, N=128, H=8, Dh=64, FEA=512)
#define FEA 512
#define NH 8
#define DH 64
#define BB 2
#define TT 128
#define NN 128
#define MTOT (BB*TT*NN)     // 32768 rows
#define SEG 16              // T / H
#define BETA 0.3f
#define LNEPS 1e-5f

typedef __attribute__((ext_vector_type(8))) _Float16 f16x8; // MFMA A/B frag (4 VGPRs)
typedef __attribute__((ext_vector_type(4))) float f32x4;    // MFMA C/D frag
typedef __attribute__((ext_vector_type(8))) short s16x8;    // 16B vector ld/st

static __device__ __forceinline__ ushort f2h(float x) {     // RTNE fp32->fp16
  _Float16 h = (_Float16)x;
  return __builtin_bit_cast(ushort, h);
}
static __device__ __forceinline__ float h2f(ushort u) {     // exact fp16->fp32
  return (float)__builtin_bit_cast(_Float16, u);
}

// ---------------------------------------------------------------------------
// xt = x + te -> fp16 only (control dispatch, unchanged; ~52 µs)
// ---------------------------------------------------------------------------
__global__ __launch_bounds__(256) void add_h(const float* __restrict__ x,
                                             const float* __restrict__ te,
                                             ushort* __restrict__ xth) {
  size_t i = ((size_t)blockIdx.x * 256 + threadIdx.x) * 8;
  float4 a0 = *(const float4*)&x[i];
  float4 a1 = *(const float4*)&x[i + 4];
  float4 b0 = *(const float4*)&te[i];
  float4 b1 = *(const float4*)&te[i + 4];
  s16x8 o;
  o[0]=(short)f2h(a0.x+b0.x); o[1]=(short)f2h(a0.y+b0.y);
  o[2]=(short)f2h(a0.z+b0.z); o[3]=(short)f2h(a0.w+b0.w);
  o[4]=(short)f2h(a1.x+b1.x); o[5]=(short)f2h(a1.y+b1.y);
  o[6]=(short)f2h(a1.z+b1.z); o[7]=(short)f2h(a1.w+b1.w);
  *(s16x8*)&xth[i] = o;
}

// ---------------------------------------------------------------------------
// Convert + transpose all 6 weights fp32 [k][n] -> fp16 WT [n][k].
// ---------------------------------------------------------------------------
struct W6 { const float* s[6]; };

__global__ __launch_bounds__(256) void wconv(W6 w, ushort* __restrict__ dst) {
  __shared__ float t[32][33];
  const float* W = w.s[blockIdx.z];
  ushort* WT = dst + (size_t)blockIdx.z * FEA * FEA;
  const int k0 = blockIdx.y * 32, n0 = blockIdx.x * 32;
  const int tx = threadIdx.x & 31, ty = threadIdx.x >> 5;   // 32 x 8
  #pragma unroll
  for (int i = 0; i < 4; ++i)
    t[ty + i * 8][tx] = W[(size_t)(k0 + ty + i * 8) * FEA + n0 + tx];
  __syncthreads();
  #pragma unroll
  for (int i = 0; i < 4; ++i)
    WT[(size_t)(n0 + ty + i * 8) * FEA + k0 + tx] = f2h(t[tx][ty + i * 8]);
}

// ---------------------------------------------------------------------------
// C[M,512](fp16) = A[M,512](fp16) @ WT^T + bias(f32), optional relu.
// 128x128 tile, BK=32, 2-phase double-buffered (round 7), 4 waves 2x2.
// NEW (T1): 1D grid + bijective XCD-chunked swizzle. Works are ordered
// x-fastest (n/weight) within each m-tile; wl=(bid&7)*(NWG/8)+bid/8 gives
// each XCD a contiguous run of works -> the XS blocks sharing an A-tile run
// concurrently on ONE XCD; W (<=3 MB) stays L2-resident. A fetched once.
// ---------------------------------------------------------------------------
struct GArgs {
  const ushort* wt[3];
  const float* bias[3];
  ushort* out[3];
};

template<int RELU, int NW, int NWG>
__global__ __launch_bounds__(256) void gemm_h(const ushort* __restrict__ A, GArgs p) {
  __shared__ ushort As[2][4096];
  __shared__ ushort Bs[2][4096];
  const int tid = threadIdx.x;
  // XCD-chunked bijective swizzle (NWG % 8 == 0)
  constexpr int CPX = NWG / 8;
  constexpr int XS = (NW == 3) ? 12 : 4;          // works per m-tile (x-fastest)
  const int wl = (blockIdx.x & 7) * CPX + (blockIdx.x >> 3);
  const int xw = wl % XS;
  const int m0 = (wl / XS) * 128;
  const int wsel = (NW == 3) ? (xw >> 2) : 0;
  const int n0 = ((NW == 3) ? (xw & 3) : xw) * 128;
  const ushort* __restrict__ WT = p.wt[wsel];
  const float*  __restrict__ bias = p.bias[wsel];
  ushort* __restrict__ C = p.out[wsel];
  const int lane = tid & 63;
  const int wid = tid >> 6;
  const int wm = wid >> 1, wn = wid & 1;          // 2x2 wave grid (64x64 each)
  const int c = lane & 15, g = lane >> 4;         // frag row, k-group

  f32x4 acc[4][4] = {};                           // [m-frag][n-frag], D = C^T

  // Staging map: LDS slot i (16B) <- global (r = i>>2, kq = (i&3) ^ ((r>>1)&3))
  int r_[2], kq_[2];
  #pragma unroll
  for (int cc = 0; cc < 2; ++cc) {
    int i = cc * 256 + tid;
    r_[cc] = i >> 2;
    kq_[cc] = (i & 3) ^ ((r_[cc] >> 1) & 3);
  }

  auto stage = [&](int buf, int k0) {
    #pragma unroll
    for (int cc = 0; cc < 2; ++cc) {
      const ushort* ga = A  + (size_t)(m0 + r_[cc]) * 512 + k0 + kq_[cc] * 8;
      const ushort* gb = WT + (size_t)(n0 + r_[cc]) * 512 + k0 + kq_[cc] * 8;
      __builtin_amdgcn_global_load_lds(
          (const __attribute__((address_space(1))) void*)ga,
          (__attribute__((address_space(3))) void*)&As[buf][(cc * 256 + tid) * 8], 16, 0, 0);
      __builtin_amdgcn_global_load_lds(
          (const __attribute__((address_space(1))) void*)gb,
          (__attribute__((address_space(3))) void*)&Bs[buf][(cc * 256 + tid) * 8], 16, 0, 0);
    }
  };

  stage(0, 0);
  __syncthreads();                                // buf0 resident
  int cur = 0;
  for (int t = 0; t < 16; ++t) {
    if (t < 15) stage(cur ^ 1, (t + 1) * 32);     // prefetch next tile

    f16x8 af[4], bfr[4];
    #pragma unroll
    for (int s = 0; s < 4; ++s) {
      int ra = wm * 64 + s * 16 + c;
      int sa = ra * 4 + (g ^ ((ra >> 1) & 3));
      af[s] = *(const f16x8*)&As[cur][sa * 8];
      int rb = wn * 64 + s * 16 + c;
      int sb = rb * 4 + (g ^ ((rb >> 1) & 3));
      bfr[s] = *(const f16x8*)&Bs[cur][sb * 8];
    }
    #pragma unroll
    for (int i = 0; i < 4; ++i)
      #pragma unroll
      for (int j = 0; j < 4; ++j)
        acc[i][j] = __builtin_amdgcn_mfma_f32_16x16x32_f16(bfr[j], af[i], acc[i][j], 0, 0, 0);

    __syncthreads();                              // drains vmcnt: next tile ready
    cur ^= 1;
  }

  // Epilogue: lane (g,c) frag (i,j) holds C[m0+wm*64+i*16+c][n0+wn*64+j*16+g*4+reg]
  float4 bv4[4];
  #pragma unroll
  for (int j = 0; j < 4; ++j)
    bv4[j] = *(const float4*)&bias[n0 + wn * 64 + j * 16 + g * 4];
  #pragma unroll
  for (int i = 0; i < 4; ++i) {
    const size_t rb = (size_t)(m0 + wm * 64 + i * 16 + c) * 512;
    #pragma unroll
    for (int j = 0; j < 4; ++j) {
      const int nb = n0 + wn * 64 + j * 16 + g * 4;
      float o0 = acc[i][j][0] + bv4[j].x;
      float o1 = acc[i][j][1] + bv4[j].y;
      float o2 = acc[i][j][2] + bv4[j].z;
      float o3 = acc[i][j][3] + bv4[j].w;
      if (RELU) {
        o0 = fmaxf(o0, 0.f); o1 = fmaxf(o1, 0.f);
        o2 = fmaxf(o2, 0.f); o3 = fmaxf(o3, 0.f);
      }
      uint2 pk;
      pk.x = (uint)f2h(o0) | ((uint)f2h(o1) << 16);
      pk.y = (uint)f2h(o2) | ((uint)f2h(o3) << 16);
      *(uint2*)&C[rb + nb] = pk;
    }
  }
}

// ---------------------------------------------------------------------------
// MFMA attention (fp16). Unchanged (control; < 51 µs).
// ---------------------------------------------------------------------------
__global__ __launch_bounds__(256) void attn_mfma(const ushort* __restrict__ kp,
                                                 const ushort* __restrict__ vp,
                                                 ushort* __restrict__ qo) {
  __shared__ ushort Ks[8192];      // 128t x 64d, 16B slots: slot(t,gs)=t*8+(gs^(t&7))
  __shared__ ushort Vt[8192];      // V^T 64d x 128t: slot(d,ts)=d*16+(ts^(d&7)^(d>>3))
  __shared__ ushort Pb[4][1024];   // per-wave P [32q][32t]: slot(qr,ts)=qr*4+(ts^(qr&3))
  __shared__ float  Lb[4][32];     // per-wave 1/l

  const int bid = blockIdx.x;
  const int h = bid & 7;
  const int n = (bid >> 3) & 127;
  const int b = bid >> 10;
  const int tid = threadIdx.x;
  const int lane = tid & 63;
  const int w = tid >> 6;
  const int g = lane >> 4, c = lane & 15;
  const size_t tstride = (size_t)NN * FEA;
  const size_t base = ((size_t)b * TT * NN + n) * FEA + (size_t)h * DH;

  #pragma unroll
  for (int it = 0; it < 4; ++it) {
    int i = it * 256 + tid;
    int t = i >> 3;
    int gd = (i & 7) ^ (t & 7);
    const ushort* gk = kp + base + (size_t)t * tstride + gd * 8;
    __builtin_amdgcn_global_load_lds(
        (const __attribute__((address_space(1))) void*)gk,
        (__attribute__((address_space(3))) void*)&Ks[i * 8], 16, 0, 0);
  }
  #pragma unroll
  for (int it = 0; it < 4; ++it) {
    int j = it * 256 + tid;
    int t = j >> 3, d0 = (j & 7) * 8;
    s16x8 vv = *(const s16x8*)&vp[base + (size_t)t * tstride + d0];
    #pragma unroll
    for (int jj = 0; jj < 8; ++jj) {
      int d = d0 + jj;
      int slot = d * 16 + ((t >> 3) ^ (d & 7) ^ (d >> 3));
      Vt[slot * 8 + (t & 7)] = (ushort)vv[jj];
    }
  }
  const int qb = w * 32;
  f16x8 Qf[2][2];
  #pragma unroll
  for (int qt = 0; qt < 2; ++qt)
    #pragma unroll
    for (int kf = 0; kf < 2; ++kf)
      Qf[qt][kf] = *(const f16x8*)
          &qo[base + (size_t)(qb + qt * 16 + c) * tstride + kf * 32 + g * 8];
  __syncthreads();   // drains vmcnt (global_load_lds) + lgkm

  const int fs = h * SEG;
  const int fe = (h == NH - 1) ? TT : fs + SEG;

  f32x4 Oa[2][4];
  #pragma unroll
  for (int qt = 0; qt < 2; ++qt)
    #pragma unroll
    for (int dt = 0; dt < 4; ++dt)
      Oa[qt][dt] = (f32x4){0.f, 0.f, 0.f, 0.f};
  float lsum[2] = {0.f, 0.f};

  for (int ch = 0; ch <= w; ++ch) {
    const int tc = ch * 32;
    f32x4 sf[2][2];
    #pragma unroll
    for (int tt2 = 0; tt2 < 2; ++tt2) {
      f16x8 Kf[2];
      #pragma unroll
      for (int kf = 0; kf < 2; ++kf) {
        int t = tc + tt2 * 16 + c;                    // A-frag row = c
        int slot = t * 8 + ((kf * 4 + g) ^ (c & 7));  // t&7 == c&7
        Kf[kf] = *(const f16x8*)&Ks[slot * 8];
      }
      #pragma unroll
      for (int qt = 0; qt < 2; ++qt) {
        f32x4 s = (f32x4){0.f, 0.f, 0.f, 0.f};
        s = __builtin_amdgcn_mfma_f32_16x16x32_f16(Kf[0], Qf[qt][0], s, 0, 0, 0);
        s = __builtin_amdgcn_mfma_f32_16x16x32_f16(Kf[1], Qf[qt][1], s, 0, 0, 0);
        sf[tt2][qt] = s;
      }
    }
    #pragma unroll
    for (int tt2 = 0; tt2 < 2; ++tt2) {
      #pragma unroll
      for (int qt = 0; qt < 2; ++qt) {
        const int q = qb + qt * 16 + c;               // D col = q
        const int qr = qt * 16 + c;                   // P-buf row
        #pragma unroll
        for (int pr = 0; pr < 2; ++pr) {
          float pv[2];
          #pragma unroll
          for (int rr = 0; rr < 2; ++rr) {
            int reg = pr * 2 + rr;
            int t = tc + tt2 * 16 + g * 4 + reg;      // D row = t
            float mult = (t >= fs && t < fe) ? 0.125f : 0.125f * BETA;
            float p = __expf(sf[tt2][qt][reg] * mult);
            p = (t <= q) ? p : 0.f;
            pv[rr] = p;
            lsum[qt] += p;
          }
          uint pk = (uint)f2h(pv[0]) | ((uint)f2h(pv[1]) << 16);
          int tl = tt2 * 16 + g * 4 + pr * 2;
          int slot = qr * 4 + ((tl >> 3) ^ (qr & 3));
          *(uint*)&Pb[w][slot * 8 + (tl & 7)] = pk;
        }
      }
    }
    f16x8 Vf[4];
    #pragma unroll
    for (int dt = 0; dt < 4; ++dt) {
      int d = dt * 16 + c;                            // B-frag col = d
      int slot = d * 16 + ((((tc >> 3)) + g) ^ (d & 7) ^ (d >> 3));
      Vf[dt] = *(const f16x8*)&Vt[slot * 8];
    }
    #pragma unroll
    for (int qt = 0; qt < 2; ++qt) {
      int qr = qt * 16 + c;                           // A-frag row = q
      int slot = qr * 4 + (g ^ (qr & 3));
      f16x8 Pa = *(const f16x8*)&Pb[w][slot * 8];
      #pragma unroll
      for (int dt = 0; dt < 4; ++dt)
        Oa[qt][dt] = __builtin_amdgcn_mfma_f32_16x16x32_f16(Pa, Vf[dt], Oa[qt][dt], 0, 0, 0);
    }
  }

  #pragma unroll
  for (int qt = 0; qt < 2; ++qt) {
    lsum[qt] += __shfl_xor(lsum[qt], 16, 64);
    lsum[qt] += __shfl_xor(lsum[qt], 32, 64);
  }
  if (g == 0) {
    Lb[w][c]      = 1.0f / lsum[0];
    Lb[w][16 + c] = 1.0f / lsum[1];
  }
  #pragma unroll
  for (int qt = 0; qt < 2; ++qt) {
    f32x4 linv = *(const f32x4*)&Lb[w][qt * 16 + g * 4];
    #pragma unroll
    for (int dt = 0; dt < 4; ++dt) {
      #pragma unroll
      for (int reg = 0; reg < 4; ++reg) {
        int q = qb + qt * 16 + g * 4 + reg;           // D row = q
        qo[base + (size_t)q * tstride + dt * 16 + c] = f2h(Oa[qt][dt][reg] * linv[reg]);
      }
    }
  }
}

// ---------------------------------------------------------------------------
// y = LayerNorm(a + r) over last dim 512; one wave/row, 4 rows/block.
// ---------------------------------------------------------------------------
template<int AH, int RH, int OH>
__global__ __launch_bounds__(256) void ln_add(const void* __restrict__ a_,
                                              const void* __restrict__ r_,
                                              void* __restrict__ y_) {
  const int lane = threadIdx.x & 63;
  const int w = threadIdx.x >> 6;
  const size_t row = (size_t)blockIdx.x * 4 + w;
  const size_t off = row * FEA + (size_t)lane * 8;
  float ua[8], ur[8], u[8];
  if (AH) {
    s16x8 v = *(const s16x8*)&((const ushort*)a_)[off];
    #pragma unroll
    for (int j = 0; j < 8; ++j) ua[j] = h2f((ushort)v[j]);
  } else {
    float4 v0 = *(const float4*)&((const float*)a_)[off];
    float4 v1 = *(const float4*)&((const float*)a_)[off + 4];
    ua[0]=v0.x; ua[1]=v0.y; ua[2]=v0.z; ua[3]=v0.w;
    ua[4]=v1.x; ua[5]=v1.y; ua[6]=v1.z; ua[7]=v1.w;
  }
  if (RH) {
    s16x8 v = *(const s16x8*)&((const ushort*)r_)[off];
    #pragma unroll
    for (int j = 0; j < 8; ++j) ur[j] = h2f((ushort)v[j]);
  } else {
    float4 v0 = *(const float4*)&((const float*)r_)[off];
    float4 v1 = *(const float4*)&((const float*)r_)[off + 4];
    ur[0]=v0.x; ur[1]=v0.y; ur[2]=v0.z; ur[3]=v0.w;
    ur[4]=v1.x; ur[5]=v1.y; ur[6]=v1.z; ur[7]=v1.w;
  }
  float sum = 0.f, sq = 0.f;
  #pragma unroll
  for (int j = 0; j < 8; ++j) {
    u[j] = ua[j] + ur[j];
    sum += u[j];
    sq = fmaf(u[j], u[j], sq);
  }
  #pragma unroll
  for (int m = 1; m < 64; m <<= 1) {
    sum += __shfl_xor(sum, m, 64);
    sq  += __shfl_xor(sq,  m, 64);
  }
  const float mean = sum * (1.0f / FEA);
  const float var = sq * (1.0f / FEA) - mean * mean;
  const float rstd = rsqrtf(var + LNEPS);
  if (OH) {
    s16x8 o;
    #pragma unroll
    for (int j = 0; j < 8; ++j) o[j] = (short)f2h((u[j] - mean) * rstd);
    *(s16x8*)&((ushort*)y_)[off] = o;
  } else {
    float4 o0, o1;
    o0.x=(u[0]-mean)*rstd; o0.y=(u[1]-mean)*rstd; o0.z=(u[2]-mean)*rstd; o0.w=(u[3]-mean)*rstd;
    o1.x=(u[4]-mean)*rstd; o1.y=(u[5]-mean)*rstd; o1.z=(u[6]-mean)*rstd; o1.w=(u[7]-mean)*rstd;
    *(float4*)&((float*)y_)[off] = o0;
    *(float4*)&((float*)y_)[off + 4] = o1;
  }
}

// ---------------------------------------------------------------------------
// Orchestration. ws (131 MiB): B0..B3 fp16 buffers (32 MiB each) + WB (3 MiB).
//   B0: xt_h -> y (step 6)   B1: q -> attnout -> h2   B2: k -> out1   B3: v -> h
// ---------------------------------------------------------------------------
extern "C" void kernel_launch(void* const* d_in, const int* in_sizes, int n_in,
                              void* d_out, int out_size, void* d_ws, size_t ws_size,
                              hipStream_t stream) {
  const float* x  = (const float*)d_in[0];
  const float* te = (const float*)d_in[1];
  const float* bq = (const float*)d_in[3];
  const float* bk = (const float*)d_in[5];
  const float* bv = (const float*)d_in[7];
  const float* bo = (const float*)d_in[9];
  const float* b1 = (const float*)d_in[11];
  const float* b2 = (const float*)d_in[13];
  float* out = (float*)d_out;

  const size_t E = (size_t)MTOT * FEA;           // 16,777,216
  ushort* B0 = (ushort*)d_ws;
  ushort* B1 = B0 + E;
  ushort* B2 = B1 + E;
  ushort* B3 = B2 + E;
  ushort* WB = B3 + E;                           // 6 x 512 x 512
  const size_t WE = (size_t)FEA * FEA;

  // 1. xt = x + te -> fp16
  add_h<<<E / 8 / 256, 256, 0, stream>>>(x, te, B0);
  // 2. weights -> fp16, transposed
  W6 w;
  w.s[0] = (const float*)d_in[2];  w.s[1] = (const float*)d_in[4];
  w.s[2] = (const float*)d_in[6];  w.s[3] = (const float*)d_in[8];
  w.s[4] = (const float*)d_in[10]; w.s[5] = (const float*)d_in[12];
  wconv<<<dim3(16, 16, 6), 256, 0, stream>>>(w, WB);
  // 3. fused q,k,v GEMM (1D grid 3072, XCD-chunked swizzle)
  GArgs gqkv;
  gqkv.wt[0] = WB;          gqkv.bias[0] = bq; gqkv.out[0] = B1;
  gqkv.wt[1] = WB + WE;     gqkv.bias[1] = bk; gqkv.out[1] = B2;
  gqkv.wt[2] = WB + 2 * WE; gqkv.bias[2] = bv; gqkv.out[2] = B3;
  gemm_h<0, 3, 3072><<<3072, 256, 0, stream>>>(B0, gqkv);
  // 4. attention (MFMA, in-place over q)
  attn_mfma<<<BB * NN * NH, 256, 0, stream>>>(B2, B3, B1);
  // 5. out1 = attn @ Wo + bo
  GArgs go = {};
  go.wt[0] = WB + 3 * WE; go.bias[0] = bo; go.out[0] = B2;
  gemm_h<0, 1, 1024><<<1024, 256, 0, stream>>>(B1, go);
  // 6. y = LN(out1 + xt) -> fp16, in-place over B0
  ln_add<1, 1, 1><<<MTOT / 4, 256, 0, stream>>>(B2, B0, B0);
  // 7. h = relu(y @ W1 + b1)
  GArgs g1 = {};
  g1.wt[0] = WB + 4 * WE; g1.bias[0] = b1; g1.out[0] = B3;
  gemm_h<1, 1, 1024><<<1024, 256, 0, stream>>>(B0, g1);
  // 8. h2 = h @ W2 + b2
  GArgs g2 = {};
  g2.wt[0] = WB + 5 * WE; g2.bias[0] = b2; g2.out[0] = B1;
  gemm_h<0, 1, 1024><<<1024, 256, 0, stream>>>(B3, g2);
  // 9. out = LN(h2 + y) -> fp32
  ln_add<1, 1, 0><<<MTOT / 4, 256, 0, stream>>>(B1, B0, out);
}

// Round 9
// 405.751 us; speedup vs baseline: 3.9332x; 1.0633x over previous
//
#include <hip/hip_runtime.h>
#include <math.h>

typedef unsigned int uint;
typedef unsigned short ushort;

// Problem constants (reference: B=2, T=128, N=128, H=8, Dh=64, FEA=512)
#define FEA 512
#define NH 8
#define DH 64
#define BB 2
#define TT 128
#define NN 128
#define MTOT (BB*TT*NN)     // 32768 rows
#define SEG 16              // T / H
#define BETA 0.3f
#define LNEPS 1e-5f

typedef __attribute__((ext_vector_type(8))) _Float16 f16x8; // MFMA A/B frag (4 VGPRs)
typedef __attribute__((ext_vector_type(4))) float f32x4;    // MFMA C/D frag
typedef __attribute__((ext_vector_type(8))) short s16x8;    // 16B vector ld/st

static __device__ __forceinline__ ushort f2h(float x) {     // RTNE fp32->fp16
  _Float16 h = (_Float16)x;
  return __builtin_bit_cast(ushort, h);
}
static __device__ __forceinline__ float h2f(ushort u) {     // exact fp16->fp32
  return (float)__builtin_bit_cast(_Float16, u);
}

// ---------------------------------------------------------------------------
// xt = x + te -> fp16. 2 chunks/thread (8 independent 16B loads in flight)
// to raise MLP; grid halved to 4096 blocks.
// ---------------------------------------------------------------------------
__global__ __launch_bounds__(256) void add_h(const float* __restrict__ x,
                                             const float* __restrict__ te,
                                             ushort* __restrict__ xth) {
  const size_t half = (size_t)MTOT * FEA / 2;
  size_t i0 = ((size_t)blockIdx.x * 256 + threadIdx.x) * 8;
  size_t i1 = i0 + half;
  float4 a0 = *(const float4*)&x[i0];
  float4 a1 = *(const float4*)&x[i0 + 4];
  float4 c0 = *(const float4*)&x[i1];
  float4 c1 = *(const float4*)&x[i1 + 4];
  float4 b0 = *(const float4*)&te[i0];
  float4 b1 = *(const float4*)&te[i0 + 4];
  float4 d0 = *(const float4*)&te[i1];
  float4 d1 = *(const float4*)&te[i1 + 4];
  s16x8 o0, o1;
  o0[0]=(short)f2h(a0.x+b0.x); o0[1]=(short)f2h(a0.y+b0.y);
  o0[2]=(short)f2h(a0.z+b0.z); o0[3]=(short)f2h(a0.w+b0.w);
  o0[4]=(short)f2h(a1.x+b1.x); o0[5]=(short)f2h(a1.y+b1.y);
  o0[6]=(short)f2h(a1.z+b1.z); o0[7]=(short)f2h(a1.w+b1.w);
  o1[0]=(short)f2h(c0.x+d0.x); o1[1]=(short)f2h(c0.y+d0.y);
  o1[2]=(short)f2h(c0.z+d0.z); o1[3]=(short)f2h(c0.w+d0.w);
  o1[4]=(short)f2h(c1.x+d1.x); o1[5]=(short)f2h(c1.y+d1.y);
  o1[6]=(short)f2h(c1.z+d1.z); o1[7]=(short)f2h(c1.w+d1.w);
  *(s16x8*)&xth[i0] = o0;
  *(s16x8*)&xth[i1] = o1;
}

// ---------------------------------------------------------------------------
// Convert + transpose all 6 weights fp32 [k][n] -> fp16 WT [n][k].
// ---------------------------------------------------------------------------
struct W6 { const float* s[6]; };

__global__ __launch_bounds__(256) void wconv(W6 w, ushort* __restrict__ dst) {
  __shared__ float t[32][33];
  const float* W = w.s[blockIdx.z];
  ushort* WT = dst + (size_t)blockIdx.z * FEA * FEA;
  const int k0 = blockIdx.y * 32, n0 = blockIdx.x * 32;
  const int tx = threadIdx.x & 31, ty = threadIdx.x >> 5;   // 32 x 8
  #pragma unroll
  for (int i = 0; i < 4; ++i)
    t[ty + i * 8][tx] = W[(size_t)(k0 + ty + i * 8) * FEA + n0 + tx];
  __syncthreads();
  #pragma unroll
  for (int i = 0; i < 4; ++i)
    WT[(size_t)(n0 + ty + i * 8) * FEA + k0 + tx] = f2h(t[tx][ty + i * 8]);
}

// ---------------------------------------------------------------------------
// C[M,512](fp16) = A[M,512](fp16) @ WT^T + bias(f32), optional relu.
// 128x128 tile, BK=32, 4 waves 2x2, XCD-chunked swizzle (T1, round 8).
// NEW (T4): depth-2 counted-vmcnt pipeline. Prologue stages k=0,1 (8 loads
// in flight). Per iter: ds_read frags(buf t) -> lgkmcnt(0)+sched_barrier+
// s_barrier (buffer dead across ALL waves) -> stage(t+2) into it -> 16 MFMA
// -> vmcnt(4) (stage t+1 done, t+2 STAYS in flight; never drain 0) ->
// s_barrier. Fully unrolled so waits are compile-time constants.
// ---------------------------------------------------------------------------
struct GArgs {
  const ushort* wt[3];
  const float* bias[3];
  ushort* out[3];
};

template<int RELU, int NW, int NWG>
__global__ __launch_bounds__(256) void gemm_h(const ushort* __restrict__ A, GArgs p) {
  __shared__ ushort As[2][4096];
  __shared__ ushort Bs[2][4096];
  const int tid = threadIdx.x;
  // XCD-chunked bijective swizzle (NWG % 8 == 0)
  constexpr int CPX = NWG / 8;
  constexpr int XS = (NW == 3) ? 12 : 4;          // works per m-tile (x-fastest)
  const int wl = (blockIdx.x & 7) * CPX + (blockIdx.x >> 3);
  const int xw = wl % XS;
  const int m0 = (wl / XS) * 128;
  const int wsel = (NW == 3) ? (xw >> 2) : 0;
  const int n0 = ((NW == 3) ? (xw & 3) : xw) * 128;
  const ushort* __restrict__ WT = p.wt[wsel];
  const float*  __restrict__ bias = p.bias[wsel];
  ushort* __restrict__ C = p.out[wsel];
  const int lane = tid & 63;
  const int wid = tid >> 6;
  const int wm = wid >> 1, wn = wid & 1;          // 2x2 wave grid (64x64 each)
  const int c = lane & 15, g = lane >> 4;         // frag row, k-group

  f32x4 acc[4][4] = {};                           // [m-frag][n-frag], D = C^T

  // Staging map: LDS slot i (16B) <- global (r = i>>2, kq = (i&3) ^ ((r>>1)&3))
  int r_[2], kq_[2];
  #pragma unroll
  for (int cc = 0; cc < 2; ++cc) {
    int i = cc * 256 + tid;
    r_[cc] = i >> 2;
    kq_[cc] = (i & 3) ^ ((r_[cc] >> 1) & 3);
  }

  auto stage = [&](int buf, int k0) {
    #pragma unroll
    for (int cc = 0; cc < 2; ++cc) {
      const ushort* ga = A  + (size_t)(m0 + r_[cc]) * 512 + k0 + kq_[cc] * 8;
      const ushort* gb = WT + (size_t)(n0 + r_[cc]) * 512 + k0 + kq_[cc] * 8;
      __builtin_amdgcn_global_load_lds(
          (const __attribute__((address_space(1))) void*)ga,
          (__attribute__((address_space(3))) void*)&As[buf][(cc * 256 + tid) * 8], 16, 0, 0);
      __builtin_amdgcn_global_load_lds(
          (const __attribute__((address_space(1))) void*)gb,
          (__attribute__((address_space(3))) void*)&Bs[buf][(cc * 256 + tid) * 8], 16, 0, 0);
    }
  };

  // Prologue: stage tiles 0 and 1; wait tile 0 only (4 of 8 outstanding).
  stage(0, 0);
  stage(1, 32);
  asm volatile("s_waitcnt vmcnt(4)" ::: "memory");
  __builtin_amdgcn_sched_barrier(0);
  __builtin_amdgcn_s_barrier();

  #pragma unroll
  for (int t = 0; t < 16; ++t) {
    const int bi = t & 1;

    f16x8 af[4], bfr[4];
    #pragma unroll
    for (int s = 0; s < 4; ++s) {
      int ra = wm * 64 + s * 16 + c;
      int sa = ra * 4 + (g ^ ((ra >> 1) & 3));
      af[s] = *(const f16x8*)&As[bi][sa * 8];
      int rb = wn * 64 + s * 16 + c;
      int sb = rb * 4 + (g ^ ((rb >> 1) & 3));
      bfr[s] = *(const f16x8*)&Bs[bi][sb * 8];
    }
    // My frags in regs; barrier => ALL waves done reading buf bi => dead.
    asm volatile("s_waitcnt lgkmcnt(0)" ::: "memory");
    __builtin_amdgcn_sched_barrier(0);
    __builtin_amdgcn_s_barrier();

    if (t + 2 < 16) stage(bi, (t + 2) * 32);      // overwrite dead buffer

    #pragma unroll
    for (int i = 0; i < 4; ++i)
      #pragma unroll
      for (int j = 0; j < 4; ++j)
        acc[i][j] = __builtin_amdgcn_mfma_f32_16x16x32_f16(bfr[j], af[i], acc[i][j], 0, 0, 0);

    if (t < 15) {
      // Tile t+1 resident: its 4 loads are the oldest outstanding.
      if (t < 14) { asm volatile("s_waitcnt vmcnt(4)" ::: "memory"); }
      else        { asm volatile("s_waitcnt vmcnt(0)" ::: "memory"); }
      __builtin_amdgcn_sched_barrier(0);
      __builtin_amdgcn_s_barrier();
    }
  }

  // Epilogue: lane (g,c) frag (i,j) holds C[m0+wm*64+i*16+c][n0+wn*64+j*16+g*4+reg]
  float4 bv4[4];
  #pragma unroll
  for (int j = 0; j < 4; ++j)
    bv4[j] = *(const float4*)&bias[n0 + wn * 64 + j * 16 + g * 4];
  #pragma unroll
  for (int i = 0; i < 4; ++i) {
    const size_t rb = (size_t)(m0 + wm * 64 + i * 16 + c) * 512;
    #pragma unroll
    for (int j = 0; j < 4; ++j) {
      const int nb = n0 + wn * 64 + j * 16 + g * 4;
      float o0 = acc[i][j][0] + bv4[j].x;
      float o1 = acc[i][j][1] + bv4[j].y;
      float o2 = acc[i][j][2] + bv4[j].z;
      float o3 = acc[i][j][3] + bv4[j].w;
      if (RELU) {
        o0 = fmaxf(o0, 0.f); o1 = fmaxf(o1, 0.f);
        o2 = fmaxf(o2, 0.f); o3 = fmaxf(o3, 0.f);
      }
      uint2 pk;
      pk.x = (uint)f2h(o0) | ((uint)f2h(o1) << 16);
      pk.y = (uint)f2h(o2) | ((uint)f2h(o3) << 16);
      *(uint2*)&C[rb + nb] = pk;
    }
  }
}

// ---------------------------------------------------------------------------
// MFMA attention (fp16). Unchanged (control; < 51 µs).
// ---------------------------------------------------------------------------
__global__ __launch_bounds__(256) void attn_mfma(const ushort* __restrict__ kp,
                                                 const ushort* __restrict__ vp,
                                                 ushort* __restrict__ qo) {
  __shared__ ushort Ks[8192];      // 128t x 64d, 16B slots: slot(t,gs)=t*8+(gs^(t&7))
  __shared__ ushort Vt[8192];      // V^T 64d x 128t: slot(d,ts)=d*16+(ts^(d&7)^(d>>3))
  __shared__ ushort Pb[4][1024];   // per-wave P [32q][32t]: slot(qr,ts)=qr*4+(ts^(qr&3))
  __shared__ float  Lb[4][32];     // per-wave 1/l

  const int bid = blockIdx.x;
  const int h = bid & 7;
  const int n = (bid >> 3) & 127;
  const int b = bid >> 10;
  const int tid = threadIdx.x;
  const int lane = tid & 63;
  const int w = tid >> 6;
  const int g = lane >> 4, c = lane & 15;
  const size_t tstride = (size_t)NN * FEA;
  const size_t base = ((size_t)b * TT * NN + n) * FEA + (size_t)h * DH;

  #pragma unroll
  for (int it = 0; it < 4; ++it) {
    int i = it * 256 + tid;
    int t = i >> 3;
    int gd = (i & 7) ^ (t & 7);
    const ushort* gk = kp + base + (size_t)t * tstride + gd * 8;
    __builtin_amdgcn_global_load_lds(
        (const __attribute__((address_space(1))) void*)gk,
        (__attribute__((address_space(3))) void*)&Ks[i * 8], 16, 0, 0);
  }
  #pragma unroll
  for (int it = 0; it < 4; ++it) {
    int j = it * 256 + tid;
    int t = j >> 3, d0 = (j & 7) * 8;
    s16x8 vv = *(const s16x8*)&vp[base + (size_t)t * tstride + d0];
    #pragma unroll
    for (int jj = 0; jj < 8; ++jj) {
      int d = d0 + jj;
      int slot = d * 16 + ((t >> 3) ^ (d & 7) ^ (d >> 3));
      Vt[slot * 8 + (t & 7)] = (ushort)vv[jj];
    }
  }
  const int qb = w * 32;
  f16x8 Qf[2][2];
  #pragma unroll
  for (int qt = 0; qt < 2; ++qt)
    #pragma unroll
    for (int kf = 0; kf < 2; ++kf)
      Qf[qt][kf] = *(const f16x8*)
          &qo[base + (size_t)(qb + qt * 16 + c) * tstride + kf * 32 + g * 8];
  __syncthreads();   // drains vmcnt (global_load_lds) + lgkm

  const int fs = h * SEG;
  const int fe = (h == NH - 1) ? TT : fs + SEG;

  f32x4 Oa[2][4];
  #pragma unroll
  for (int qt = 0; qt < 2; ++qt)
    #pragma unroll
    for (int dt = 0; dt < 4; ++dt)
      Oa[qt][dt] = (f32x4){0.f, 0.f, 0.f, 0.f};
  float lsum[2] = {0.f, 0.f};

  for (int ch = 0; ch <= w; ++ch) {
    const int tc = ch * 32;
    f32x4 sf[2][2];
    #pragma unroll
    for (int tt2 = 0; tt2 < 2; ++tt2) {
      f16x8 Kf[2];
      #pragma unroll
      for (int kf = 0; kf < 2; ++kf) {
        int t = tc + tt2 * 16 + c;                    // A-frag row = c
        int slot = t * 8 + ((kf * 4 + g) ^ (c & 7));  // t&7 == c&7
        Kf[kf] = *(const f16x8*)&Ks[slot * 8];
      }
      #pragma unroll
      for (int qt = 0; qt < 2; ++qt) {
        f32x4 s = (f32x4){0.f, 0.f, 0.f, 0.f};
        s = __builtin_amdgcn_mfma_f32_16x16x32_f16(Kf[0], Qf[qt][0], s, 0, 0, 0);
        s = __builtin_amdgcn_mfma_f32_16x16x32_f16(Kf[1], Qf[qt][1], s, 0, 0, 0);
        sf[tt2][qt] = s;
      }
    }
    #pragma unroll
    for (int tt2 = 0; tt2 < 2; ++tt2) {
      #pragma unroll
      for (int qt = 0; qt < 2; ++qt) {
        const int q = qb + qt * 16 + c;               // D col = q
        const int qr = qt * 16 + c;                   // P-buf row
        #pragma unroll
        for (int pr = 0; pr < 2; ++pr) {
          float pv[2];
          #pragma unroll
          for (int rr = 0; rr < 2; ++rr) {
            int reg = pr * 2 + rr;
            int t = tc + tt2 * 16 + g * 4 + reg;      // D row = t
            float mult = (t >= fs && t < fe) ? 0.125f : 0.125f * BETA;
            float p = __expf(sf[tt2][qt][reg] * mult);
            p = (t <= q) ? p : 0.f;
            pv[rr] = p;
            lsum[qt] += p;
          }
          uint pk = (uint)f2h(pv[0]) | ((uint)f2h(pv[1]) << 16);
          int tl = tt2 * 16 + g * 4 + pr * 2;
          int slot = qr * 4 + ((tl >> 3) ^ (qr & 3));
          *(uint*)&Pb[w][slot * 8 + (tl & 7)] = pk;
        }
      }
    }
    f16x8 Vf[4];
    #pragma unroll
    for (int dt = 0; dt < 4; ++dt) {
      int d = dt * 16 + c;                            // B-frag col = d
      int slot = d * 16 + ((((tc >> 3)) + g) ^ (d & 7) ^ (d >> 3));
      Vf[dt] = *(const f16x8*)&Vt[slot * 8];
    }
    #pragma unroll
    for (int qt = 0; qt < 2; ++qt) {
      int qr = qt * 16 + c;                           // A-frag row = q
      int slot = qr * 4 + (g ^ (qr & 3));
      f16x8 Pa = *(const f16x8*)&Pb[w][slot * 8];
      #pragma unroll
      for (int dt = 0; dt < 4; ++dt)
        Oa[qt][dt] = __builtin_amdgcn_mfma_f32_16x16x32_f16(Pa, Vf[dt], Oa[qt][dt], 0, 0, 0);
    }
  }

  #pragma unroll
  for (int qt = 0; qt < 2; ++qt) {
    lsum[qt] += __shfl_xor(lsum[qt], 16, 64);
    lsum[qt] += __shfl_xor(lsum[qt], 32, 64);
  }
  if (g == 0) {
    Lb[w][c]      = 1.0f / lsum[0];
    Lb[w][16 + c] = 1.0f / lsum[1];
  }
  #pragma unroll
  for (int qt = 0; qt < 2; ++qt) {
    f32x4 linv = *(const f32x4*)&Lb[w][qt * 16 + g * 4];
    #pragma unroll
    for (int dt = 0; dt < 4; ++dt) {
      #pragma unroll
      for (int reg = 0; reg < 4; ++reg) {
        int q = qb + qt * 16 + g * 4 + reg;           // D row = q
        qo[base + (size_t)q * tstride + dt * 16 + c] = f2h(Oa[qt][dt][reg] * linv[reg]);
      }
    }
  }
}

// ---------------------------------------------------------------------------
// y = LayerNorm(a + r) over last dim 512; one wave/row, 4 rows/block.
// ---------------------------------------------------------------------------
template<int AH, int RH, int OH>
__global__ __launch_bounds__(256) void ln_add(const void* __restrict__ a_,
                                              const void* __restrict__ r_,
                                              void* __restrict__ y_) {
  const int lane = threadIdx.x & 63;
  const int w = threadIdx.x >> 6;
  const size_t row = (size_t)blockIdx.x * 4 + w;
  const size_t off = row * FEA + (size_t)lane * 8;
  float ua[8], ur[8], u[8];
  if (AH) {
    s16x8 v = *(const s16x8*)&((const ushort*)a_)[off];
    #pragma unroll
    for (int j = 0; j < 8; ++j) ua[j] = h2f((ushort)v[j]);
  } else {
    float4 v0 = *(const float4*)&((const float*)a_)[off];
    float4 v1 = *(const float4*)&((const float*)a_)[off + 4];
    ua[0]=v0.x; ua[1]=v0.y; ua[2]=v0.z; ua[3]=v0.w;
    ua[4]=v1.x; ua[5]=v1.y; ua[6]=v1.z; ua[7]=v1.w;
  }
  if (RH) {
    s16x8 v = *(const s16x8*)&((const ushort*)r_)[off];
    #pragma unroll
    for (int j = 0; j < 8; ++j) ur[j] = h2f((ushort)v[j]);
  } else {
    float4 v0 = *(const float4*)&((const float*)r_)[off];
    float4 v1 = *(const float4*)&((const float*)r_)[off + 4];
    ur[0]=v0.x; ur[1]=v0.y; ur[2]=v0.z; ur[3]=v0.w;
    ur[4]=v1.x; ur[5]=v1.y; ur[6]=v1.z; ur[7]=v1.w;
  }
  float sum = 0.f, sq = 0.f;
  #pragma unroll
  for (int j = 0; j < 8; ++j) {
    u[j] = ua[j] + ur[j];
    sum += u[j];
    sq = fmaf(u[j], u[j], sq);
  }
  #pragma unroll
  for (int m = 1; m < 64; m <<= 1) {
    sum += __shfl_xor(sum, m, 64);
    sq  += __shfl_xor(sq,  m, 64);
  }
  const float mean = sum * (1.0f / FEA);
  const float var = sq * (1.0f / FEA) - mean * mean;
  const float rstd = rsqrtf(var + LNEPS);
  if (OH) {
    s16x8 o;
    #pragma unroll
    for (int j = 0; j < 8; ++j) o[j] = (short)f2h((u[j] - mean) * rstd);
    *(s16x8*)&((ushort*)y_)[off] = o;
  } else {
    float4 o0, o1;
    o0.x=(u[0]-mean)*rstd; o0.y=(u[1]-mean)*rstd; o0.z=(u[2]-mean)*rstd; o0.w=(u[3]-mean)*rstd;
    o1.x=(u[4]-mean)*rstd; o1.y=(u[5]-mean)*rstd; o1.z=(u[6]-mean)*rstd; o1.w=(u[7]-mean)*rstd;
    *(float4*)&((float*)y_)[off] = o0;
    *(float4*)&((float*)y_)[off + 4] = o1;
  }
}

// ---------------------------------------------------------------------------
// Orchestration. ws (131 MiB): B0..B3 fp16 buffers (32 MiB each) + WB (3 MiB).
//   B0: xt_h -> y (step 6)   B1: q -> attnout -> h2   B2: k -> out1   B3: v -> h
// ---------------------------------------------------------------------------
extern "C" void kernel_launch(void* const* d_in, const int* in_sizes, int n_in,
                              void* d_out, int out_size, void* d_ws, size_t ws_size,
                              hipStream_t stream) {
  const float* x  = (const float*)d_in[0];
  const float* te = (const float*)d_in[1];
  const float* bq = (const float*)d_in[3];
  const float* bk = (const float*)d_in[5];
  const float* bv = (const float*)d_in[7];
  const float* bo = (const float*)d_in[9];
  const float* b1 = (const float*)d_in[11];
  const float* b2 = (const float*)d_in[13];
  float* out = (float*)d_out;

  const size_t E = (size_t)MTOT * FEA;           // 16,777,216
  ushort* B0 = (ushort*)d_ws;
  ushort* B1 = B0 + E;
  ushort* B2 = B1 + E;
  ushort* B3 = B2 + E;
  ushort* WB = B3 + E;                           // 6 x 512 x 512
  const size_t WE = (size_t)FEA * FEA;

  // 1. xt = x + te -> fp16 (2 chunks/thread)
  add_h<<<E / 16 / 256, 256, 0, stream>>>(x, te, B0);
  // 2. weights -> fp16, transposed
  W6 w;
  w.s[0] = (const float*)d_in[2];  w.s[1] = (const float*)d_in[4];
  w.s[2] = (const float*)d_in[6];  w.s[3] = (const float*)d_in[8];
  w.s[4] = (const float*)d_in[10]; w.s[5] = (const float*)d_in[12];
  wconv<<<dim3(16, 16, 6), 256, 0, stream>>>(w, WB);
  // 3. fused q,k,v GEMM (1D grid 3072, XCD-chunked swizzle)
  GArgs gqkv;
  gqkv.wt[0] = WB;          gqkv.bias[0] = bq; gqkv.out[0] = B1;
  gqkv.wt[1] = WB + WE;     gqkv.bias[1] = bk; gqkv.out[1] = B2;
  gqkv.wt[2] = WB + 2 * WE; gqkv.bias[2] = bv; gqkv.out[2] = B3;
  gemm_h<0, 3, 3072><<<3072, 256, 0, stream>>>(B0, gqkv);
  // 4. attention (MFMA, in-place over q)
  attn_mfma<<<BB * NN * NH, 256, 0, stream>>>(B2, B3, B1);
  // 5. out1 = attn @ Wo + bo
  GArgs go = {};
  go.wt[0] = WB + 3 * WE; go.bias[0] = bo; go.out[0] = B2;
  gemm_h<0, 1, 1024><<<1024, 256, 0, stream>>>(B1, go);
  // 6. y = LN(out1 + xt) -> fp16, in-place over B0
  ln_add<1, 1, 1><<<MTOT / 4, 256, 0, stream>>>(B2, B0, B0);
  // 7. h = relu(y @ W1 + b1)
  GArgs g1 = {};
  g1.wt[0] = WB + 4 * WE; g1.bias[0] = b1; g1.out[0] = B3;
  gemm_h<1, 1, 1024><<<1024, 256, 0, stream>>>(B0, g1);
  // 8. h2 = h @ W2 + b2
  GArgs g2 = {};
  g2.wt[0] = WB + 5 * WE; g2.bias[0] = b2; g2.out[0] = B1;
  gemm_h<0, 1, 1024><<<1024, 256, 0, stream>>>(B3, g2);
  // 9. out = LN(h2 + y) -> fp32
  ln_add<1, 1, 0><<<MTOT / 4, 256, 0, stream>>>(B1, B0, out);
}